// Round 4
// baseline (728.640 us; speedup 1.0000x reference)
//
#include <hip/hip_runtime.h>
#include <cstddef>

// TwinSAGE: 2-layer GraphSAGE (mean aggr) + twin query path + 2-way layer
// attention + output projection.
// Round 7: aggregation kernels emit PRE-SPLIT bf16 hi/lo planes (the split
// formerly done inside the GEMM k-loop via cvt_store8). GEMM job-a stages
// A1 as pure ushort8 copies (zero conversion VALU); job-b (fp32 A1) and
// the A2 path unchanged. Arithmetic bit-identical to round 6.

namespace {

constexpr int N1i  = 100000;
constexpr int Bni  = 10000;
constexpr int E0i  = 1000000;
constexpr int E1i  = 100000;
constexpr int FIN  = 128;
constexpr int HID  = 256;
constexpr int NCLS = 40;

typedef __attribute__((ext_vector_type(8))) short short8;
typedef __attribute__((ext_vector_type(8))) unsigned short ushort8;
typedef __attribute__((ext_vector_type(4))) unsigned short us4;
typedef __attribute__((ext_vector_type(4))) float floatx4;

// ---------------- fused CSR build ----------------

__global__ void hist_both_kernel(const int* __restrict__ dst0, const int* __restrict__ dst1,
                                 int* __restrict__ cnt0, int* __restrict__ cnt1) {
    int i = blockIdx.x * blockDim.x + threadIdx.x;
    if (i < E0i) atomicAdd(&cnt0[dst0[i]], 1);
    else if (i < E0i + E1i) atomicAdd(&cnt1[dst1[i - E0i]], 1);
}

__global__ void partial_sum_both_kernel(const int* __restrict__ cnt0, const int* __restrict__ cnt1,
                                        int* __restrict__ bsum0, int* __restrict__ bsum1, int nb0) {
    __shared__ int s[256];
    const int* cnt; int n; int* bsum; int bi;
    if ((int)blockIdx.x < nb0) { cnt = cnt0; n = N1i; bsum = bsum0; bi = blockIdx.x; }
    else                       { cnt = cnt1; n = Bni; bsum = bsum1; bi = blockIdx.x - nb0; }
    int i = bi * 256 + threadIdx.x;
    s[threadIdx.x] = (i < n) ? cnt[i] : 0;
    __syncthreads();
    for (int o = 128; o > 0; o >>= 1) {
        if (threadIdx.x < o) s[threadIdx.x] += s[threadIdx.x + o];
        __syncthreads();
    }
    if (threadIdx.x == 0) bsum[bi] = s[0];
}

__global__ void scan_bsum_both_kernel(int* __restrict__ bsum0, int nb0, int* __restrict__ tot0,
                                      int* __restrict__ bsum1, int nb1, int* __restrict__ tot1) {
    __shared__ int s[512];
    int* bsum; int nb; int* tot;
    if (blockIdx.x == 0) { bsum = bsum0; nb = nb0; tot = tot0; }
    else                 { bsum = bsum1; nb = nb1; tot = tot1; }
    int t = threadIdx.x;
    int v = (t < nb) ? bsum[t] : 0;
    s[t] = v;
    __syncthreads();
    for (int o = 1; o < 512; o <<= 1) {
        int u = (t >= o) ? s[t - o] : 0;
        __syncthreads();
        s[t] += u;
        __syncthreads();
    }
    if (t < nb) bsum[t] = s[t] - v;   // exclusive
    if (t == 511) *tot = s[511];
}

__global__ void scan_final_both_kernel(int* __restrict__ cnt0, const int* __restrict__ bsum0, int* __restrict__ rp0,
                                       int* __restrict__ cnt1, const int* __restrict__ bsum1, int* __restrict__ rp1,
                                       int nb0) {
    __shared__ int s[256];
    int* cnt; const int* bsum; int* rp; int n; int bi;
    if ((int)blockIdx.x < nb0) { cnt = cnt0; bsum = bsum0; rp = rp0; n = N1i; bi = blockIdx.x; }
    else                       { cnt = cnt1; bsum = bsum1; rp = rp1; n = Bni; bi = blockIdx.x - nb0; }
    int t = threadIdx.x;
    int i = bi * 256 + t;
    int v = (i < n) ? cnt[i] : 0;
    s[t] = v;
    __syncthreads();
    for (int o = 1; o < 256; o <<= 1) {
        int u = (t >= o) ? s[t - o] : 0;
        __syncthreads();
        s[t] += u;
        __syncthreads();
    }
    if (i < n) {
        int r = bsum[bi] + s[t] - v;  // exclusive
        rp[i]  = r;
        cnt[i] = r;                   // cursor for scatter
    }
}

__global__ void scatter_both_kernel(const int* __restrict__ src0, const int* __restrict__ dst0,
                                    const int* __restrict__ src1, const int* __restrict__ dst1,
                                    int* __restrict__ cur0, int* __restrict__ cur1,
                                    int* __restrict__ es0, int* __restrict__ es1) {
    int i = blockIdx.x * blockDim.x + threadIdx.x;
    if (i < E0i) {
        int p = atomicAdd(&cur0[dst0[i]], 1);
        es0[p] = src0[i];
    } else if (i < E0i + E1i) {
        int j = i - E0i;
        int p = atomicAdd(&cur1[dst1[j]], 1);
        es1[p] = src1[j];
    }
}

// ---------------- bf16 split helpers ----------------

__device__ inline unsigned short bf16_rne_u(unsigned u) {
    unsigned r = u + 0x7fffu + ((u >> 16) & 1u);
    return (unsigned short)(r >> 16);
}

__device__ inline void split1(float f, unsigned short& hs, unsigned short& ls) {
    hs = bf16_rne_u(__float_as_uint(f));
    float lo = f - __uint_as_float((unsigned)hs << 16);
    ls = bf16_rne_u(__float_as_uint(lo));
}

// ---------------- Mean aggregation (emit split hi/lo planes) ----------

// agg_mean128: one wave per target; each dwordx4 load covers TWO source
// rows (half-wave per row). Padded 8-instr batches with validity weights.
// Epilogue: mean -> bf16 hi/lo split -> planes [M][128] shorts.
__global__ __launch_bounds__(256) void agg_mean128_kernel(
    const float* __restrict__ x, const int* __restrict__ rp,
    const int* __restrict__ es,
    unsigned short* __restrict__ aggh, unsigned short* __restrict__ aggl, int ntgt) {
    int tgt  = blockIdx.x * 4 + (threadIdx.x >> 6);
    int lane = threadIdx.x & 63;
    if (tgt >= ntgt) return;
    int b = rp[tgt], e = rp[tgt + 1];
    int d = e - b;
    int half = lane >> 5;
    int sl   = lane & 31;
    float4 acc = {0.f, 0.f, 0.f, 0.f};
    const float* xp = x + sl * 4;
    for (int base = 0; base < d; base += 64) {
        int rem = d - base; if (rem > 64) rem = 64;
        int li  = lane < rem ? lane : rem - 1;
        int idx = es[b + base + li];
        int rm1 = rem - 1;
        int npair = (rem + 1) >> 1;
        for (int p = 0; p < npair; p += 8) {
            int e0 = p * 2 + half;
            int s0 = e0      <= rm1 ? e0      : rm1;
            int s1 = e0 + 2  <= rm1 ? e0 + 2  : rm1;
            int s2 = e0 + 4  <= rm1 ? e0 + 4  : rm1;
            int s3 = e0 + 6  <= rm1 ? e0 + 6  : rm1;
            int s4 = e0 + 8  <= rm1 ? e0 + 8  : rm1;
            int s5 = e0 + 10 <= rm1 ? e0 + 10 : rm1;
            int s6 = e0 + 12 <= rm1 ? e0 + 12 : rm1;
            int s7 = e0 + 14 <= rm1 ? e0 + 14 : rm1;
            float w0 = (e0      < rem) ? 1.f : 0.f;
            float w1 = (e0 + 2  < rem) ? 1.f : 0.f;
            float w2 = (e0 + 4  < rem) ? 1.f : 0.f;
            float w3 = (e0 + 6  < rem) ? 1.f : 0.f;
            float w4 = (e0 + 8  < rem) ? 1.f : 0.f;
            float w5 = (e0 + 10 < rem) ? 1.f : 0.f;
            float w6 = (e0 + 12 < rem) ? 1.f : 0.f;
            float w7 = (e0 + 14 < rem) ? 1.f : 0.f;
            int i0 = __shfl(idx, s0), i1 = __shfl(idx, s1);
            int i2 = __shfl(idx, s2), i3 = __shfl(idx, s3);
            int i4 = __shfl(idx, s4), i5 = __shfl(idx, s5);
            int i6 = __shfl(idx, s6), i7 = __shfl(idx, s7);
            float4 v0 = *(const float4*)(xp + i0 * FIN);
            float4 v1 = *(const float4*)(xp + i1 * FIN);
            float4 v2 = *(const float4*)(xp + i2 * FIN);
            float4 v3 = *(const float4*)(xp + i3 * FIN);
            float4 v4 = *(const float4*)(xp + i4 * FIN);
            float4 v5 = *(const float4*)(xp + i5 * FIN);
            float4 v6 = *(const float4*)(xp + i6 * FIN);
            float4 v7 = *(const float4*)(xp + i7 * FIN);
            acc.x += v0.x * w0 + v1.x * w1 + v2.x * w2 + v3.x * w3
                   + v4.x * w4 + v5.x * w5 + v6.x * w6 + v7.x * w7;
            acc.y += v0.y * w0 + v1.y * w1 + v2.y * w2 + v3.y * w3
                   + v4.y * w4 + v5.y * w5 + v6.y * w6 + v7.y * w7;
            acc.z += v0.z * w0 + v1.z * w1 + v2.z * w2 + v3.z * w3
                   + v4.z * w4 + v5.z * w5 + v6.z * w6 + v7.z * w7;
            acc.w += v0.w * w0 + v1.w * w1 + v2.w * w2 + v3.w * w3
                   + v4.w * w4 + v5.w * w5 + v6.w * w6 + v7.w * w7;
        }
    }
    acc.x += __shfl_xor(acc.x, 32);
    acc.y += __shfl_xor(acc.y, 32);
    acc.z += __shfl_xor(acc.z, 32);
    acc.w += __shfl_xor(acc.w, 32);
    if (lane < 32) {
        float inv = 1.0f / fmaxf((float)d, 1.0f);
        float f[4] = {acc.x * inv, acc.y * inv, acc.z * inv, acc.w * inv};
        us4 hv, lv;
#pragma unroll
        for (int j = 0; j < 4; j++) { unsigned short hs, ls; split1(f[j], hs, ls); hv[j] = hs; lv[j] = ls; }
        *(us4*)(aggh + (size_t)tgt * FIN + sl * 4) = hv;
        *(us4*)(aggl + (size_t)tgt * FIN + sl * 4) = lv;
    }
}

// agg_mean256: one wave per target, full 1KB row per instruction.
// Epilogue: split planes [M][256] shorts.
__global__ __launch_bounds__(256) void agg_mean256_kernel(
    const float* __restrict__ h, const int* __restrict__ rp,
    const int* __restrict__ es,
    unsigned short* __restrict__ aggh, unsigned short* __restrict__ aggl, int ntgt) {
    int tgt  = blockIdx.x * 4 + (threadIdx.x >> 6);
    int lane = threadIdx.x & 63;
    if (tgt >= ntgt) return;
    int b = rp[tgt], e = rp[tgt + 1];
    int d = e - b;
    float4 acc = {0.f, 0.f, 0.f, 0.f};
    const float* hp = h + lane * 4;
    for (int base = 0; base < d; base += 64) {
        int rem = d - base; if (rem > 64) rem = 64;
        int li  = lane < rem ? lane : rem - 1;
        int idx = es[b + base + li];
        int rm1 = rem - 1;
        for (int j = 0; j < rem; j += 8) {
            int s0 = j     <= rm1 ? j     : rm1;
            int s1 = j + 1 <= rm1 ? j + 1 : rm1;
            int s2 = j + 2 <= rm1 ? j + 2 : rm1;
            int s3 = j + 3 <= rm1 ? j + 3 : rm1;
            int s4 = j + 4 <= rm1 ? j + 4 : rm1;
            int s5 = j + 5 <= rm1 ? j + 5 : rm1;
            int s6 = j + 6 <= rm1 ? j + 6 : rm1;
            int s7 = j + 7 <= rm1 ? j + 7 : rm1;
            float w0 = 1.f;
            float w1 = (j + 1 < rem) ? 1.f : 0.f;
            float w2 = (j + 2 < rem) ? 1.f : 0.f;
            float w3 = (j + 3 < rem) ? 1.f : 0.f;
            float w4 = (j + 4 < rem) ? 1.f : 0.f;
            float w5 = (j + 5 < rem) ? 1.f : 0.f;
            float w6 = (j + 6 < rem) ? 1.f : 0.f;
            float w7 = (j + 7 < rem) ? 1.f : 0.f;
            int i0 = __shfl(idx, s0), i1 = __shfl(idx, s1);
            int i2 = __shfl(idx, s2), i3 = __shfl(idx, s3);
            int i4 = __shfl(idx, s4), i5 = __shfl(idx, s5);
            int i6 = __shfl(idx, s6), i7 = __shfl(idx, s7);
            float4 v0 = *(const float4*)(hp + i0 * HID);
            float4 v1 = *(const float4*)(hp + i1 * HID);
            float4 v2 = *(const float4*)(hp + i2 * HID);
            float4 v3 = *(const float4*)(hp + i3 * HID);
            float4 v4 = *(const float4*)(hp + i4 * HID);
            float4 v5 = *(const float4*)(hp + i5 * HID);
            float4 v6 = *(const float4*)(hp + i6 * HID);
            float4 v7 = *(const float4*)(hp + i7 * HID);
            acc.x += v0.x * w0 + v1.x * w1 + v2.x * w2 + v3.x * w3
                   + v4.x * w4 + v5.x * w5 + v6.x * w6 + v7.x * w7;
            acc.y += v0.y * w0 + v1.y * w1 + v2.y * w2 + v3.y * w3
                   + v4.y * w4 + v5.y * w5 + v6.y * w6 + v7.y * w7;
            acc.z += v0.z * w0 + v1.z * w1 + v2.z * w2 + v3.z * w3
                   + v4.z * w4 + v5.z * w5 + v6.z * w6 + v7.z * w7;
            acc.w += v0.w * w0 + v1.w * w1 + v2.w * w2 + v3.w * w3
                   + v4.w * w4 + v5.w * w5 + v6.w * w6 + v7.w * w7;
        }
    }
    float inv = 1.0f / fmaxf((float)d, 1.0f);
    float f[4] = {acc.x * inv, acc.y * inv, acc.z * inv, acc.w * inv};
    us4 hv, lv;
#pragma unroll
    for (int j = 0; j < 4; j++) { unsigned short hs, ls; split1(f[j], hs, ls); hv[j] = hs; lv[j] = ls; }
    *(us4*)(aggh + (size_t)tgt * HID + lane * 4) = hv;
    *(us4*)(aggl + (size_t)tgt * HID + lane * 4) = lv;
}

// ---------------- weight transpose + bf16 hi/lo split (fused x4) --------

__global__ void wtrans_all_kernel(const float* __restrict__ W1l, const float* __restrict__ W1r,
                                  const float* __restrict__ W2l, const float* __restrict__ W2r,
                                  unsigned short* __restrict__ w1lh, unsigned short* __restrict__ w1ll,
                                  unsigned short* __restrict__ w1rh, unsigned short* __restrict__ w1rl,
                                  unsigned short* __restrict__ w2lh, unsigned short* __restrict__ w2ll,
                                  unsigned short* __restrict__ w2rh, unsigned short* __restrict__ w2rl) {
    int e = blockIdx.x * 256 + threadIdx.x;
    const float* W; unsigned short* hiT; unsigned short* loT; int K; int idx;
    if (e < 65536) {
        K = 128;
        if (e < 32768) { W = W1l; hiT = w1lh; loT = w1ll; idx = e; }
        else           { W = W1r; hiT = w1rh; loT = w1rl; idx = e - 32768; }
    } else {
        K = 256;
        int e2 = e - 65536;
        if (e2 < 65536) { W = W2l; hiT = w2lh; loT = w2ll; idx = e2; }
        else            { W = W2r; hiT = w2rh; loT = w2rl; idx = e2 - 65536; }
    }
    int k = idx >> 8, n = idx & 255;
    unsigned short hs, ls;
    split1(W[idx], hs, ls);
    hiT[n * K + k] = hs;
    loT[n * K + k] = ls;
}

// ---------------- unified split-bf16 MFMA GEMM ----------------
// C[M x 256] = relu(A1@B1 + A2@B2 + bias).
// Job a: A1 PRE-SPLIT bf16 hi/lo planes [M][K1] (pure ushort8 staging),
//        A2 fp32 row-major (in-loop split).
// Job b: A1 fp32 only (K2=0).
// B pre-split/transposed bf16 hi/lo [256][K].
// 3-term: Ahi*Bhi + Ahi*Blo + Alo*Bhi. Block 128x256, 8 waves, BK=32,
// reg prefetch of next k-tile.

__device__ inline void cvt_store8(unsigned short* hi_dst, unsigned short* lo_dst,
                                  const float* v) {
    ushort8 hv, lv;
#pragma unroll
    for (int i = 0; i < 8; i++) {
        unsigned short hs, ls;
        split1(v[i], hs, ls);
        hv[i] = hs;
        lv[i] = ls;
    }
    *(ushort8*)hi_dst = hv;
    *(ushort8*)lo_dst = lv;
}

__global__ __launch_bounds__(512, 2) void gemm_dual_kernel(
    const unsigned short* __restrict__ A1ha, const unsigned short* __restrict__ A1la,
    const float* __restrict__ A2a,
    const unsigned short* __restrict__ B1ha, const unsigned short* __restrict__ B1la,
    const unsigned short* __restrict__ B2ha, const unsigned short* __restrict__ B2la,
    const float* __restrict__ biasa, float* __restrict__ Ca, int Ma, int K1a, int K2a, int nmba,
    const float* __restrict__ A1fb,
    const unsigned short* __restrict__ B1hb, const unsigned short* __restrict__ B1lb,
    float* __restrict__ Cb, int Mb, int K1b) {
    constexpr int LDAS = 40;  // bf16 elems per LDS row (+8 pad)
    __shared__ __align__(16) unsigned short Ah[128 * LDAS];
    __shared__ __align__(16) unsigned short Al[128 * LDAS];
    __shared__ __align__(16) unsigned short Bh[256 * LDAS];
    __shared__ __align__(16) unsigned short Bl[256 * LDAS];

    const unsigned short *A1h, *A1l;       // job a (split)
    const float *A1f, *A2;                 // job b / job a second term
    const unsigned short *B1h, *B1l, *B2h, *B2l;
    const float* bias; float* C; int M, K1, K2;
    bool jobA;
    int mb = blockIdx.x;
    if (mb < nmba) {
        jobA = true;
        A1h = A1ha; A1l = A1la; A1f = nullptr; A2 = A2a;
        B1h = B1ha; B1l = B1la; B2h = B2ha; B2l = B2la;
        bias = biasa; C = Ca; M = Ma; K1 = K1a; K2 = K2a;
    } else {
        jobA = false;
        mb -= nmba;
        A1h = nullptr; A1l = nullptr; A1f = A1fb; A2 = nullptr;
        B1h = B1hb; B1l = B1lb; B2h = nullptr; B2l = nullptr;
        bias = nullptr; C = Cb; M = Mb; K1 = K1b; K2 = 0;
    }
    const int Kt = K1 + K2;
    const int m0 = mb * 128;

    const int tid  = threadIdx.x;
    const int lane = tid & 63;
    const int wave = tid >> 6;
    const int wm   = (wave & 1) * 64;
    const int wn   = (wave >> 1) * 64;
    const int arow_l = tid >> 2;         // 0..127, 4 threads per A row
    const int acol   = (tid & 3) * 8;    // 8 elems each
    const int brow   = tid >> 1;         // 0..255, 2 threads per B row
    const int bcol   = (tid & 1) * 16;   // 16 shorts each
    const int frow = lane & 15;
    const int fk   = (lane >> 4) * 8;

    int arow = m0 + arow_l; if (arow >= M) arow = M - 1;

    floatx4 acc[4][4] = {};

    // prologue: prefetch k-tile 0
    float4 pa0, pa1;          // fp32 A prefetch (job b A1 / job a A2)
    ushort8 pah, pal;         // split A prefetch (job a A1)
    ushort8 ph0, ph1, pl0, pl1;
    if (jobA) {
        pah = *(const ushort8*)(A1h + (size_t)arow * K1 + acol);
        pal = *(const ushort8*)(A1l + (size_t)arow * K1 + acol);
    } else {
        const float* ap = A1f + (size_t)arow * K1 + acol;
        pa0 = *(const float4*)(ap);
        pa1 = *(const float4*)(ap + 4);
    }
    {
        const unsigned short* bhp = B1h + (size_t)brow * K1 + bcol;
        const unsigned short* blp = B1l + (size_t)brow * K1 + bcol;
        ph0 = *(const ushort8*)bhp;       ph1 = *(const ushort8*)(bhp + 8);
        pl0 = *(const ushort8*)blp;       pl1 = *(const ushort8*)(blp + 8);
    }

    for (int k0 = 0; k0 < Kt; k0 += 32) {
        bool splitPhase = jobA && (k0 < K1);
        __syncthreads();   // prior iteration's LDS reads complete
        if (splitPhase) {
            *(ushort8*)&Ah[arow_l * LDAS + acol] = pah;
            *(ushort8*)&Al[arow_l * LDAS + acol] = pal;
        } else {
            float av[8] = {pa0.x, pa0.y, pa0.z, pa0.w, pa1.x, pa1.y, pa1.z, pa1.w};
            cvt_store8(&Ah[arow_l * LDAS + acol], &Al[arow_l * LDAS + acol], av);
        }
        *(ushort8*)&Bh[brow * LDAS + bcol]     = ph0;
        *(ushort8*)&Bh[brow * LDAS + bcol + 8] = ph1;
        *(ushort8*)&Bl[brow * LDAS + bcol]     = pl0;
        *(ushort8*)&Bl[brow * LDAS + bcol + 8] = pl1;
        __syncthreads();
        // issue next k-tile's global loads now: latency hides under MFMA
        if (k0 + 32 < Kt) {
            int kn = k0 + 32;
            if (kn < K1) {
                if (jobA) {
                    pah = *(const ushort8*)(A1h + (size_t)arow * K1 + kn + acol);
                    pal = *(const ushort8*)(A1l + (size_t)arow * K1 + kn + acol);
                } else {
                    const float* ap = A1f + (size_t)arow * K1 + kn + acol;
                    pa0 = *(const float4*)(ap);
                    pa1 = *(const float4*)(ap + 4);
                }
                const unsigned short* bhp = B1h + (size_t)brow * K1 + kn + bcol;
                const unsigned short* blp = B1l + (size_t)brow * K1 + kn + bcol;
                ph0 = *(const ushort8*)bhp;   ph1 = *(const ushort8*)(bhp + 8);
                pl0 = *(const ushort8*)blp;   pl1 = *(const ushort8*)(blp + 8);
            } else {
                int kk = kn - K1;
                const float* ap = A2 + (size_t)arow * K2 + kk + acol;
                pa0 = *(const float4*)(ap);
                pa1 = *(const float4*)(ap + 4);
                const unsigned short* bhp = B2h + (size_t)brow * K2 + kk + bcol;
                const unsigned short* blp = B2l + (size_t)brow * K2 + kk + bcol;
                ph0 = *(const ushort8*)bhp;   ph1 = *(const ushort8*)(bhp + 8);
                pl0 = *(const ushort8*)blp;   pl1 = *(const ushort8*)(blp + 8);
            }
        }

        short8 ahf[4], alf[4], bhf[4], blf[4];
#pragma unroll
        for (int t = 0; t < 4; t++) {
            int ar = (wm + t * 16 + frow) * LDAS + fk;
            ahf[t] = *(const short8*)&Ah[ar];
            alf[t] = *(const short8*)&Al[ar];
            int br = (wn + t * 16 + frow) * LDAS + fk;
            bhf[t] = *(const short8*)&Bh[br];
            blf[t] = *(const short8*)&Bl[br];
        }
#pragma unroll
        for (int i = 0; i < 4; i++) {
#pragma unroll
            for (int j = 0; j < 4; j++) {
                acc[i][j] = __builtin_amdgcn_mfma_f32_16x16x32_bf16(ahf[i], bhf[j], acc[i][j], 0, 0, 0);
                acc[i][j] = __builtin_amdgcn_mfma_f32_16x16x32_bf16(ahf[i], blf[j], acc[i][j], 0, 0, 0);
                acc[i][j] = __builtin_amdgcn_mfma_f32_16x16x32_bf16(alf[i], bhf[j], acc[i][j], 0, 0, 0);
            }
        }
    }

    const int colL = lane & 15;
    const int quad = lane >> 4;
#pragma unroll
    for (int j = 0; j < 4; j++) {
        int c = wn + j * 16 + colL;
        float bj = bias ? bias[c] : 0.0f;
#pragma unroll
        for (int i = 0; i < 4; i++) {
            int rbase = m0 + wm + i * 16 + quad * 4;
#pragma unroll
            for (int r = 0; r < 4; r++) {
                int row = rbase + r;
                if (row < M) {
                    float v = acc[i][j][r] + bj;
                    v = fmaxf(v, 0.0f);
                    C[(size_t)row * 256 + c] = v;
                }
            }
        }
    }
}

// ---------------- Fused attention + output projection ----------------

__global__ __launch_bounds__(256) void attn_out_kernel(
    const float* __restrict__ h, const float* __restrict__ h2,
    const float* __restrict__ q1, const float* __restrict__ q2,
    const float* __restrict__ Wout, const float* __restrict__ bout,
    float* __restrict__ out, int Bn) {
    int w = threadIdx.x >> 6, lane = threadIdx.x & 63;
    int row = blockIdx.x * 4 + w;
    __shared__ __align__(16) float cbuf[4][260];
    if (row < Bn) {
        const float4 a = *(const float4*)(h  + (size_t)row * HID + lane * 4);
        const float4 p = *(const float4*)(q1 + (size_t)row * HID + lane * 4);
        const float4 b = *(const float4*)(h2 + (size_t)row * HID + lane * 4);
        const float4 q = *(const float4*)(q2 + (size_t)row * HID + lane * 4);
        float s0 = a.x * p.x + a.y * p.y + a.z * p.z + a.w * p.w;
        float s1 = b.x * q.x + b.y * q.y + b.z * q.z + b.w * q.w;
        for (int o = 32; o > 0; o >>= 1) {
            s0 += __shfl_xor(s0, o);
            s1 += __shfl_xor(s1, o);
        }
        float m  = fmaxf(s0, s1);
        float e0 = __expf(s0 - m), e1 = __expf(s1 - m);
        float inv = 1.0f / (e0 + e1);
        float a0 = e0 * inv, a1 = e1 * inv;
        float4 cv;
        cv.x = a0 * a.x + a1 * b.x; cv.y = a0 * a.y + a1 * b.y;
        cv.z = a0 * a.z + a1 * b.z; cv.w = a0 * a.w + a1 * b.w;
        *(float4*)&cbuf[w][lane * 4] = cv;
    }
    __syncthreads();
    int t = threadIdx.x;
    if (t < 4 * NCLS) {
        int r = t / NCLS, j = t % NCLS;
        int orow = blockIdx.x * 4 + r;
        if (orow < Bn) {
            float acc = bout[j];
#pragma unroll 8
            for (int k = 0; k < HID; k++) acc += cbuf[r][k] * Wout[k * NCLS + j];
            out[(size_t)orow * NCLS + j] = acc;
        }
    }
}

}  // namespace

extern "C" void kernel_launch(void* const* d_in, const int* in_sizes, int n_in,
                              void* d_out, int out_size, void* d_ws, size_t ws_size,
                              hipStream_t stream) {
    const float* x    = (const float*)d_in[0];
    const int*   src0 = (const int*)d_in[1];
    const int*   dst0 = (const int*)d_in[2];
    const int*   src1 = (const int*)d_in[3];
    const int*   dst1 = (const int*)d_in[4];
    const float* W1l  = (const float*)d_in[5];
    const float* b1   = (const float*)d_in[6];
    const float* W1r  = (const float*)d_in[7];
    const float* W2l  = (const float*)d_in[8];
    const float* b2   = (const float*)d_in[9];
    const float* W2r  = (const float*)d_in[10];
    const float* Wout = (const float*)d_in[11];
    const float* bout = (const float*)d_in[12];
    float* out = (float*)d_out;

    // ---- workspace carve-up (256B-aligned) ----
    char* ws = (char*)d_ws;
    size_t off = 0;
    auto alloc = [&](size_t bytes) {
        void* p = ws + off;
        off = (off + bytes + 255) & ~(size_t)255;
        return p;
    };
    int* cnt0  = (int*)alloc((size_t)(N1i + Bni) * sizeof(int));  // contiguous: 1 memset
    int* cnt1  = cnt0 + N1i;
    int* rp0   = (int*)alloc((N1i + 1) * sizeof(int));
    int* rp1   = (int*)alloc((Bni + 1) * sizeof(int));
    int* bsum0 = (int*)alloc(512 * sizeof(int));
    int* bsum1 = (int*)alloc(512 * sizeof(int));
    int* es0   = (int*)alloc(E0i * sizeof(int));
    int* es1   = (int*)alloc(E1i * sizeof(int));
    unsigned short* w1l_hi = (unsigned short*)alloc(256 * FIN * sizeof(unsigned short));
    unsigned short* w1l_lo = (unsigned short*)alloc(256 * FIN * sizeof(unsigned short));
    unsigned short* w1r_hi = (unsigned short*)alloc(256 * FIN * sizeof(unsigned short));
    unsigned short* w1r_lo = (unsigned short*)alloc(256 * FIN * sizeof(unsigned short));
    unsigned short* w2l_hi = (unsigned short*)alloc(256 * HID * sizeof(unsigned short));
    unsigned short* w2l_lo = (unsigned short*)alloc(256 * HID * sizeof(unsigned short));
    unsigned short* w2r_hi = (unsigned short*)alloc(256 * HID * sizeof(unsigned short));
    unsigned short* w2r_lo = (unsigned short*)alloc(256 * HID * sizeof(unsigned short));
    unsigned short* agg0h = (unsigned short*)alloc((size_t)N1i * FIN * sizeof(unsigned short));
    unsigned short* agg0l = (unsigned short*)alloc((size_t)N1i * FIN * sizeof(unsigned short));
    unsigned short* agg1h = (unsigned short*)alloc((size_t)Bni * HID * sizeof(unsigned short));
    unsigned short* agg1l = (unsigned short*)alloc((size_t)Bni * HID * sizeof(unsigned short));
    float* h   = (float*)alloc((size_t)N1i * HID * sizeof(float));
    float* hq1 = (float*)alloc((size_t)Bni * HID * sizeof(float));
    float* h2  = (float*)alloc((size_t)Bni * HID * sizeof(float));
    float* h2q = (float*)alloc((size_t)Bni * HID * sizeof(float));

    const int nb0 = (N1i + 255) / 256, nb1 = (Bni + 255) / 256;
    const int nmb1g = (N1i + 127) / 128;   // 782
    const int nmbB  = (Bni + 127) / 128;   // 79

    // ---- prologue: 1 memset + 6 fused kernels ----
    hipMemsetAsync(cnt0, 0, (size_t)(N1i + Bni) * sizeof(int), stream);
    wtrans_all_kernel<<<768, 256, 0, stream>>>(W1l, W1r, W2l, W2r,
        w1l_hi, w1l_lo, w1r_hi, w1r_lo, w2l_hi, w2l_lo, w2r_hi, w2r_lo);
    hist_both_kernel<<<(E0i + E1i + 255) / 256, 256, 0, stream>>>(dst0, dst1, cnt0, cnt1);
    partial_sum_both_kernel<<<nb0 + nb1, 256, 0, stream>>>(cnt0, cnt1, bsum0, bsum1, nb0);
    scan_bsum_both_kernel<<<2, 512, 0, stream>>>(bsum0, nb0, rp0 + N1i, bsum1, nb1, rp1 + Bni);
    scan_final_both_kernel<<<nb0 + nb1, 256, 0, stream>>>(cnt0, bsum0, rp0, cnt1, bsum1, rp1, nb0);
    scatter_both_kernel<<<(E0i + E1i + 255) / 256, 256, 0, stream>>>(
        src0, dst0, src1, dst1, cnt0, cnt1, es0, es1);

    // ---- layer 1: agg (split output) + fused {h, hq1} GEMM ----
    agg_mean128_kernel<<<(N1i + 3) / 4, 256, 0, stream>>>(x, rp0, es0, agg0h, agg0l, N1i);
    gemm_dual_kernel<<<nmb1g + nmbB, 512, 0, stream>>>(
        agg0h, agg0l, x, w1l_hi, w1l_lo, w1r_hi, w1r_lo, b1, h, N1i, 128, 128, nmb1g,
        x, w1r_hi, w1r_lo, hq1, Bni, 128);

    // ---- layer 2: agg (split output) + fused {h2, h2q} GEMM ----
    agg_mean256_kernel<<<(Bni + 3) / 4, 256, 0, stream>>>(h, rp1, es1, agg1h, agg1l, Bni);
    gemm_dual_kernel<<<nmbB + nmbB, 512, 0, stream>>>(
        agg1h, agg1l, h, w2l_hi, w2l_lo, w2r_hi, w2r_lo, b2, h2, Bni, 256, 256, nmbB,
        hq1, w2r_hi, w2r_lo, h2q, Bni, 256);

    // ---- attention + output projection ----
    attn_out_kernel<<<(Bni + 3) / 4, 256, 0, stream>>>(h, h2, hq1, h2q, Wout, bout, out, Bni);
}

// Round 6
// 675.171 us; speedup vs baseline: 1.0792x; 1.0792x over previous
//
#include <hip/hip_runtime.h>
#include <cstddef>

// TwinSAGE: 2-layer GraphSAGE (mean aggr) + twin query path + 2-way layer
// attention + output projection.
// Round 9: identical to round 8 (infra retry). ROW PRUNING: layer-1 output
// h is only consumed at rows referenced by src1 or rows < B (~67K of 100K
// expected). Compacted list built inside the fused CSR kernels; agg128 and
// gemm1 job-a run over compacted slots (scattered C-write via LDS map).
// Layer-2 job-a uses an identity list. Output bit-identical to round 7.

namespace {

constexpr int N1i  = 100000;
constexpr int Bni  = 10000;
constexpr int E0i  = 1000000;
constexpr int E1i  = 100000;
constexpr int FIN  = 128;
constexpr int HID  = 256;
constexpr int NCLS = 40;

typedef __attribute__((ext_vector_type(8))) short short8;
typedef __attribute__((ext_vector_type(8))) unsigned short ushort8;
typedef __attribute__((ext_vector_type(4))) unsigned short us4;
typedef __attribute__((ext_vector_type(4))) float floatx4;

// ---------------- fused CSR build + needed-row mask ----------------

__global__ void hist_both_kernel(const int* __restrict__ dst0, const int* __restrict__ dst1,
                                 const int* __restrict__ src1,
                                 int* __restrict__ cnt0, int* __restrict__ cnt1,
                                 int* __restrict__ mask,
                                 int* __restrict__ ilist, int* __restrict__ icnt) {
    int i = blockIdx.x * blockDim.x + threadIdx.x;
    if (i < E0i) atomicAdd(&cnt0[dst0[i]], 1);
    else if (i < E0i + E1i) atomicAdd(&cnt1[dst1[i - E0i]], 1);
    else if (i < E0i + 2 * E1i) mask[src1[i - E0i - E1i]] = 1;      // plain store ok
    else if (i < E0i + 2 * E1i + Bni) {
        int j = i - E0i - 2 * E1i;
        mask[j] = 1;                                                // rows < B needed
        ilist[j] = j;                                               // identity list (layer 2)
        if (j == 0) *icnt = Bni;
    }
}

// jobs: 0 = cnt0 (N1), 1 = cnt1 (B), 2 = mask (N1)
__global__ void partial_sum_both_kernel(const int* __restrict__ cnt0, const int* __restrict__ cnt1,
                                        const int* __restrict__ mask,
                                        int* __restrict__ bsum0, int* __restrict__ bsum1,
                                        int* __restrict__ bsum2, int nb0, int nb1) {
    __shared__ int s[256];
    const int* cnt; int n; int* bsum; int bi;
    int bx = blockIdx.x;
    if (bx < nb0)            { cnt = cnt0; n = N1i; bsum = bsum0; bi = bx; }
    else if (bx < nb0 + nb1) { cnt = cnt1; n = Bni; bsum = bsum1; bi = bx - nb0; }
    else                     { cnt = mask; n = N1i; bsum = bsum2; bi = bx - nb0 - nb1; }
    int i = bi * 256 + threadIdx.x;
    s[threadIdx.x] = (i < n) ? cnt[i] : 0;
    __syncthreads();
    for (int o = 128; o > 0; o >>= 1) {
        if (threadIdx.x < o) s[threadIdx.x] += s[threadIdx.x + o];
        __syncthreads();
    }
    if (threadIdx.x == 0) bsum[bi] = s[0];
}

// grid = 3 blocks, 512 threads.
__global__ void scan_bsum_both_kernel(int* __restrict__ bsum0, int nb0, int* __restrict__ tot0,
                                      int* __restrict__ bsum1, int nb1, int* __restrict__ tot1,
                                      int* __restrict__ bsum2, int* __restrict__ tot2) {
    __shared__ int s[512];
    int* bsum; int nb; int* tot;
    if (blockIdx.x == 0)      { bsum = bsum0; nb = nb0; tot = tot0; }
    else if (blockIdx.x == 1) { bsum = bsum1; nb = nb1; tot = tot1; }
    else                      { bsum = bsum2; nb = nb0; tot = tot2; }
    int t = threadIdx.x;
    int v = (t < nb) ? bsum[t] : 0;
    s[t] = v;
    __syncthreads();
    for (int o = 1; o < 512; o <<= 1) {
        int u = (t >= o) ? s[t - o] : 0;
        __syncthreads();
        s[t] += u;
        __syncthreads();
    }
    if (t < nb) bsum[t] = s[t] - v;   // exclusive
    if (t == 511) *tot = s[511];
}

// jobs 0/1: rp + cursor. job 2: compact list of mask=1 rows (ascending).
__global__ void scan_final_both_kernel(int* __restrict__ cnt0, const int* __restrict__ bsum0, int* __restrict__ rp0,
                                       int* __restrict__ cnt1, const int* __restrict__ bsum1, int* __restrict__ rp1,
                                       const int* __restrict__ mask, const int* __restrict__ bsum2,
                                       int* __restrict__ list, int nb0, int nb1) {
    __shared__ int s[256];
    const int* cnt; const int* bsum; int n; int bi; int job;
    int bx = blockIdx.x;
    if (bx < nb0)            { job = 0; cnt = cnt0; bsum = bsum0; n = N1i; bi = bx; }
    else if (bx < nb0 + nb1) { job = 1; cnt = cnt1; bsum = bsum1; n = Bni; bi = bx - nb0; }
    else                     { job = 2; cnt = mask; bsum = bsum2; n = N1i; bi = bx - nb0 - nb1; }
    int t = threadIdx.x;
    int i = bi * 256 + t;
    int v = (i < n) ? cnt[i] : 0;
    s[t] = v;
    __syncthreads();
    for (int o = 1; o < 256; o <<= 1) {
        int u = (t >= o) ? s[t - o] : 0;
        __syncthreads();
        s[t] += u;
        __syncthreads();
    }
    if (i < n) {
        int r = bsum[bi] + s[t] - v;  // exclusive prefix
        if (job == 2) {
            if (v) list[r] = i;
        } else if (job == 0) {
            rp0[i] = r; cnt0[i] = r;  // cursor for scatter
        } else {
            rp1[i] = r; cnt1[i] = r;
        }
    }
}

__global__ void scatter_both_kernel(const int* __restrict__ src0, const int* __restrict__ dst0,
                                    const int* __restrict__ src1, const int* __restrict__ dst1,
                                    int* __restrict__ cur0, int* __restrict__ cur1,
                                    int* __restrict__ es0, int* __restrict__ es1) {
    int i = blockIdx.x * blockDim.x + threadIdx.x;
    if (i < E0i) {
        int p = atomicAdd(&cur0[dst0[i]], 1);
        es0[p] = src0[i];
    } else if (i < E0i + E1i) {
        int j = i - E0i;
        int p = atomicAdd(&cur1[dst1[j]], 1);
        es1[p] = src1[j];
    }
}

// ---------------- bf16 split helpers ----------------

__device__ inline unsigned short bf16_rne_u(unsigned u) {
    unsigned r = u + 0x7fffu + ((u >> 16) & 1u);
    return (unsigned short)(r >> 16);
}

__device__ inline void split1(float f, unsigned short& hs, unsigned short& ls) {
    hs = bf16_rne_u(__float_as_uint(f));
    float lo = f - __uint_as_float((unsigned)hs << 16);
    ls = bf16_rne_u(__float_as_uint(lo));
}

// ---------------- Mean aggregation (emit split hi/lo planes) ----------

__global__ __launch_bounds__(256) void agg_mean128_kernel(
    const float* __restrict__ x, const int* __restrict__ rp,
    const int* __restrict__ es, const int* __restrict__ list,
    const int* __restrict__ nlistp,
    unsigned short* __restrict__ aggh, unsigned short* __restrict__ aggl) {
    int slot = blockIdx.x * 4 + (threadIdx.x >> 6);
    if (slot >= *nlistp) return;          // wave-uniform
    int node = list[slot];
    int lane = threadIdx.x & 63;
    int b = rp[node], e = rp[node + 1];
    int d = e - b;
    int half = lane >> 5;
    int sl   = lane & 31;
    float4 acc = {0.f, 0.f, 0.f, 0.f};
    const float* xp = x + sl * 4;
    for (int base = 0; base < d; base += 64) {
        int rem = d - base; if (rem > 64) rem = 64;
        int li  = lane < rem ? lane : rem - 1;
        int idx = es[b + base + li];
        int rm1 = rem - 1;
        int npair = (rem + 1) >> 1;
        for (int p = 0; p < npair; p += 8) {
            int e0 = p * 2 + half;
            int s0 = e0      <= rm1 ? e0      : rm1;
            int s1 = e0 + 2  <= rm1 ? e0 + 2  : rm1;
            int s2 = e0 + 4  <= rm1 ? e0 + 4  : rm1;
            int s3 = e0 + 6  <= rm1 ? e0 + 6  : rm1;
            int s4 = e0 + 8  <= rm1 ? e0 + 8  : rm1;
            int s5 = e0 + 10 <= rm1 ? e0 + 10 : rm1;
            int s6 = e0 + 12 <= rm1 ? e0 + 12 : rm1;
            int s7 = e0 + 14 <= rm1 ? e0 + 14 : rm1;
            float w0 = (e0      < rem) ? 1.f : 0.f;
            float w1 = (e0 + 2  < rem) ? 1.f : 0.f;
            float w2 = (e0 + 4  < rem) ? 1.f : 0.f;
            float w3 = (e0 + 6  < rem) ? 1.f : 0.f;
            float w4 = (e0 + 8  < rem) ? 1.f : 0.f;
            float w5 = (e0 + 10 < rem) ? 1.f : 0.f;
            float w6 = (e0 + 12 < rem) ? 1.f : 0.f;
            float w7 = (e0 + 14 < rem) ? 1.f : 0.f;
            int i0 = __shfl(idx, s0), i1 = __shfl(idx, s1);
            int i2 = __shfl(idx, s2), i3 = __shfl(idx, s3);
            int i4 = __shfl(idx, s4), i5 = __shfl(idx, s5);
            int i6 = __shfl(idx, s6), i7 = __shfl(idx, s7);
            float4 v0 = *(const float4*)(xp + i0 * FIN);
            float4 v1 = *(const float4*)(xp + i1 * FIN);
            float4 v2 = *(const float4*)(xp + i2 * FIN);
            float4 v3 = *(const float4*)(xp + i3 * FIN);
            float4 v4 = *(const float4*)(xp + i4 * FIN);
            float4 v5 = *(const float4*)(xp + i5 * FIN);
            float4 v6 = *(const float4*)(xp + i6 * FIN);
            float4 v7 = *(const float4*)(xp + i7 * FIN);
            acc.x += v0.x * w0 + v1.x * w1 + v2.x * w2 + v3.x * w3
                   + v4.x * w4 + v5.x * w5 + v6.x * w6 + v7.x * w7;
            acc.y += v0.y * w0 + v1.y * w1 + v2.y * w2 + v3.y * w3
                   + v4.y * w4 + v5.y * w5 + v6.y * w6 + v7.y * w7;
            acc.z += v0.z * w0 + v1.z * w1 + v2.z * w2 + v3.z * w3
                   + v4.z * w4 + v5.z * w5 + v6.z * w6 + v7.z * w7;
            acc.w += v0.w * w0 + v1.w * w1 + v2.w * w2 + v3.w * w3
                   + v4.w * w4 + v5.w * w5 + v6.w * w6 + v7.w * w7;
        }
    }
    acc.x += __shfl_xor(acc.x, 32);
    acc.y += __shfl_xor(acc.y, 32);
    acc.z += __shfl_xor(acc.z, 32);
    acc.w += __shfl_xor(acc.w, 32);
    if (lane < 32) {
        float inv = 1.0f / fmaxf((float)d, 1.0f);
        float f[4] = {acc.x * inv, acc.y * inv, acc.z * inv, acc.w * inv};
        us4 hv, lv;
#pragma unroll
        for (int j = 0; j < 4; j++) { unsigned short hs, ls; split1(f[j], hs, ls); hv[j] = hs; lv[j] = ls; }
        *(us4*)(aggh + (size_t)slot * FIN + sl * 4) = hv;
        *(us4*)(aggl + (size_t)slot * FIN + sl * 4) = lv;
    }
}

__global__ __launch_bounds__(256) void agg_mean256_kernel(
    const float* __restrict__ h, const int* __restrict__ rp,
    const int* __restrict__ es,
    unsigned short* __restrict__ aggh, unsigned short* __restrict__ aggl, int ntgt) {
    int tgt  = blockIdx.x * 4 + (threadIdx.x >> 6);
    int lane = threadIdx.x & 63;
    if (tgt >= ntgt) return;
    int b = rp[tgt], e = rp[tgt + 1];
    int d = e - b;
    float4 acc = {0.f, 0.f, 0.f, 0.f};
    const float* hp = h + lane * 4;
    for (int base = 0; base < d; base += 64) {
        int rem = d - base; if (rem > 64) rem = 64;
        int li  = lane < rem ? lane : rem - 1;
        int idx = es[b + base + li];
        int rm1 = rem - 1;
        for (int j = 0; j < rem; j += 8) {
            int s0 = j     <= rm1 ? j     : rm1;
            int s1 = j + 1 <= rm1 ? j + 1 : rm1;
            int s2 = j + 2 <= rm1 ? j + 2 : rm1;
            int s3 = j + 3 <= rm1 ? j + 3 : rm1;
            int s4 = j + 4 <= rm1 ? j + 4 : rm1;
            int s5 = j + 5 <= rm1 ? j + 5 : rm1;
            int s6 = j + 6 <= rm1 ? j + 6 : rm1;
            int s7 = j + 7 <= rm1 ? j + 7 : rm1;
            float w0 = 1.f;
            float w1 = (j + 1 < rem) ? 1.f : 0.f;
            float w2 = (j + 2 < rem) ? 1.f : 0.f;
            float w3 = (j + 3 < rem) ? 1.f : 0.f;
            float w4 = (j + 4 < rem) ? 1.f : 0.f;
            float w5 = (j + 5 < rem) ? 1.f : 0.f;
            float w6 = (j + 6 < rem) ? 1.f : 0.f;
            float w7 = (j + 7 < rem) ? 1.f : 0.f;
            int i0 = __shfl(idx, s0), i1 = __shfl(idx, s1);
            int i2 = __shfl(idx, s2), i3 = __shfl(idx, s3);
            int i4 = __shfl(idx, s4), i5 = __shfl(idx, s5);
            int i6 = __shfl(idx, s6), i7 = __shfl(idx, s7);
            float4 v0 = *(const float4*)(hp + i0 * HID);
            float4 v1 = *(const float4*)(hp + i1 * HID);
            float4 v2 = *(const float4*)(hp + i2 * HID);
            float4 v3 = *(const float4*)(hp + i3 * HID);
            float4 v4 = *(const float4*)(hp + i4 * HID);
            float4 v5 = *(const float4*)(hp + i5 * HID);
            float4 v6 = *(const float4*)(hp + i6 * HID);
            float4 v7 = *(const float4*)(hp + i7 * HID);
            acc.x += v0.x * w0 + v1.x * w1 + v2.x * w2 + v3.x * w3
                   + v4.x * w4 + v5.x * w5 + v6.x * w6 + v7.x * w7;
            acc.y += v0.y * w0 + v1.y * w1 + v2.y * w2 + v3.y * w3
                   + v4.y * w4 + v5.y * w5 + v6.y * w6 + v7.y * w7;
            acc.z += v0.z * w0 + v1.z * w1 + v2.z * w2 + v3.z * w3
                   + v4.z * w4 + v5.z * w5 + v6.z * w6 + v7.z * w7;
            acc.w += v0.w * w0 + v1.w * w1 + v2.w * w2 + v3.w * w3
                   + v4.w * w4 + v5.w * w5 + v6.w * w6 + v7.w * w7;
        }
    }
    float inv = 1.0f / fmaxf((float)d, 1.0f);
    float f[4] = {acc.x * inv, acc.y * inv, acc.z * inv, acc.w * inv};
    us4 hv, lv;
#pragma unroll
    for (int j = 0; j < 4; j++) { unsigned short hs, ls; split1(f[j], hs, ls); hv[j] = hs; lv[j] = ls; }
    *(us4*)(aggh + (size_t)tgt * HID + lane * 4) = hv;
    *(us4*)(aggl + (size_t)tgt * HID + lane * 4) = lv;
}

// ---------------- weight transpose + bf16 hi/lo split (fused x4) --------

__global__ void wtrans_all_kernel(const float* __restrict__ W1l, const float* __restrict__ W1r,
                                  const float* __restrict__ W2l, const float* __restrict__ W2r,
                                  unsigned short* __restrict__ w1lh, unsigned short* __restrict__ w1ll,
                                  unsigned short* __restrict__ w1rh, unsigned short* __restrict__ w1rl,
                                  unsigned short* __restrict__ w2lh, unsigned short* __restrict__ w2ll,
                                  unsigned short* __restrict__ w2rh, unsigned short* __restrict__ w2rl) {
    int e = blockIdx.x * 256 + threadIdx.x;
    const float* W; unsigned short* hiT; unsigned short* loT; int K; int idx;
    if (e < 65536) {
        K = 128;
        if (e < 32768) { W = W1l; hiT = w1lh; loT = w1ll; idx = e; }
        else           { W = W1r; hiT = w1rh; loT = w1rl; idx = e - 32768; }
    } else {
        K = 256;
        int e2 = e - 65536;
        if (e2 < 65536) { W = W2l; hiT = w2lh; loT = w2ll; idx = e2; }
        else            { W = W2r; hiT = w2rh; loT = w2rl; idx = e2 - 65536; }
    }
    int k = idx >> 8, n = idx & 255;
    unsigned short hs, ls;
    split1(W[idx], hs, ls);
    hiT[n * K + k] = hs;
    loT[n * K + k] = ls;
}

// ---------------- unified split-bf16 MFMA GEMM (pruned job a) ----------

__device__ inline void cvt_store8(unsigned short* hi_dst, unsigned short* lo_dst,
                                  const float* v) {
    ushort8 hv, lv;
#pragma unroll
    for (int i = 0; i < 8; i++) {
        unsigned short hs, ls;
        split1(v[i], hs, ls);
        hv[i] = hs;
        lv[i] = ls;
    }
    *(ushort8*)hi_dst = hv;
    *(ushort8*)lo_dst = lv;
}

__global__ __launch_bounds__(512, 2) void gemm_dual_kernel(
    const unsigned short* __restrict__ A1ha, const unsigned short* __restrict__ A1la,
    const float* __restrict__ A2a,
    const unsigned short* __restrict__ B1ha, const unsigned short* __restrict__ B1la,
    const unsigned short* __restrict__ B2ha, const unsigned short* __restrict__ B2la,
    const float* __restrict__ biasa, float* __restrict__ Ca,
    const int* __restrict__ list, const int* __restrict__ nlistp,
    int K1a, int K2a, int nmba,
    const float* __restrict__ A1fb,
    const unsigned short* __restrict__ B1hb, const unsigned short* __restrict__ B1lb,
    float* __restrict__ Cb, int Mb, int K1b) {
    constexpr int LDAS = 40;  // bf16 elems per LDS row (+8 pad)
    __shared__ __align__(16) unsigned short Ah[128 * LDAS];
    __shared__ __align__(16) unsigned short Al[128 * LDAS];
    __shared__ __align__(16) unsigned short Bh[256 * LDAS];
    __shared__ __align__(16) unsigned short Bl[256 * LDAS];
    __shared__ int lsd[128];   // job a: slot -> node map

    const unsigned short *A1h, *A1l;
    const float *A1f, *A2;
    const unsigned short *B1h, *B1l, *B2h, *B2l;
    const float* bias; float* C; int K1, K2, M;
    bool jobA;
    int mb = blockIdx.x;
    if (mb < nmba) {
        jobA = true;
        M = *nlistp;
        if (mb * 128 >= M) return;          // block-uniform early exit
        A1h = A1ha; A1l = A1la; A1f = nullptr; A2 = A2a;
        B1h = B1ha; B1l = B1la; B2h = B2ha; B2l = B2la;
        bias = biasa; C = Ca; K1 = K1a; K2 = K2a;
    } else {
        jobA = false;
        mb -= nmba;
        M = Mb;
        A1h = nullptr; A1l = nullptr; A1f = A1fb; A2 = nullptr;
        B1h = B1hb; B1l = B1lb; B2h = nullptr; B2l = nullptr;
        bias = nullptr; C = Cb; K1 = K1b; K2 = 0;
    }
    const int Kt = K1 + K2;
    const int m0 = mb * 128;

    const int tid  = threadIdx.x;
    const int lane = tid & 63;
    const int wave = tid >> 6;
    const int wm   = (wave & 1) * 64;
    const int wn   = (wave >> 1) * 64;
    const int arow_l = tid >> 2;
    const int acol   = (tid & 3) * 8;
    const int brow   = tid >> 1;
    const int bcol   = (tid & 1) * 16;
    const int frow = lane & 15;
    const int fk   = (lane >> 4) * 8;

    int arow = m0 + arow_l; if (arow >= M) arow = M - 1;
    const int arl = arow - m0;           // clamped local row (0..127)

    if (jobA && tid < 128) {
        int s = m0 + tid;
        lsd[tid] = list[s < M ? s : M - 1];
    }
    // visibility: first lsd use is after the loop's first __syncthreads()

    floatx4 acc[4][4] = {};

    float4 pa0, pa1;
    ushort8 pah, pal;
    ushort8 ph0, ph1, pl0, pl1;
    if (jobA) {
        pah = *(const ushort8*)(A1h + (size_t)arow * K1 + acol);
        pal = *(const ushort8*)(A1l + (size_t)arow * K1 + acol);
    } else {
        const float* ap = A1f + (size_t)arow * K1 + acol;
        pa0 = *(const float4*)(ap);
        pa1 = *(const float4*)(ap + 4);
    }
    {
        const unsigned short* bhp = B1h + (size_t)brow * K1 + bcol;
        const unsigned short* blp = B1l + (size_t)brow * K1 + bcol;
        ph0 = *(const ushort8*)bhp;       ph1 = *(const ushort8*)(bhp + 8);
        pl0 = *(const ushort8*)blp;       pl1 = *(const ushort8*)(blp + 8);
    }

    for (int k0 = 0; k0 < Kt; k0 += 32) {
        bool splitPhase = jobA && (k0 < K1);
        __syncthreads();
        if (splitPhase) {
            *(ushort8*)&Ah[arow_l * LDAS + acol] = pah;
            *(ushort8*)&Al[arow_l * LDAS + acol] = pal;
        } else {
            float av[8] = {pa0.x, pa0.y, pa0.z, pa0.w, pa1.x, pa1.y, pa1.z, pa1.w};
            cvt_store8(&Ah[arow_l * LDAS + acol], &Al[arow_l * LDAS + acol], av);
        }
        *(ushort8*)&Bh[brow * LDAS + bcol]     = ph0;
        *(ushort8*)&Bh[brow * LDAS + bcol + 8] = ph1;
        *(ushort8*)&Bl[brow * LDAS + bcol]     = pl0;
        *(ushort8*)&Bl[brow * LDAS + bcol + 8] = pl1;
        __syncthreads();
        if (k0 + 32 < Kt) {
            int kn = k0 + 32;
            if (kn < K1) {
                if (jobA) {
                    pah = *(const ushort8*)(A1h + (size_t)arow * K1 + kn + acol);
                    pal = *(const ushort8*)(A1l + (size_t)arow * K1 + kn + acol);
                } else {
                    const float* ap = A1f + (size_t)arow * K1 + kn + acol;
                    pa0 = *(const float4*)(ap);
                    pa1 = *(const float4*)(ap + 4);
                }
                const unsigned short* bhp = B1h + (size_t)brow * K1 + kn + bcol;
                const unsigned short* blp = B1l + (size_t)brow * K1 + kn + bcol;
                ph0 = *(const ushort8*)bhp;   ph1 = *(const ushort8*)(bhp + 8);
                pl0 = *(const ushort8*)blp;   pl1 = *(const ushort8*)(blp + 8);
            } else {
                int kk = kn - K1;
                int anode = lsd[arl];                  // slot -> node
                const float* ap = A2 + (size_t)anode * K2 + kk + acol;
                pa0 = *(const float4*)(ap);
                pa1 = *(const float4*)(ap + 4);
                const unsigned short* bhp = B2h + (size_t)brow * K2 + kk + bcol;
                const unsigned short* blp = B2l + (size_t)brow * K2 + kk + bcol;
                ph0 = *(const ushort8*)bhp;   ph1 = *(const ushort8*)(bhp + 8);
                pl0 = *(const ushort8*)blp;   pl1 = *(const ushort8*)(blp + 8);
            }
        }

        short8 ahf[4], alf[4], bhf[4], blf[4];
#pragma unroll
        for (int t = 0; t < 4; t++) {
            int ar = (wm + t * 16 + frow) * LDAS + fk;
            ahf[t] = *(const short8*)&Ah[ar];
            alf[t] = *(const short8*)&Al[ar];
            int br = (wn + t * 16 + frow) * LDAS + fk;
            bhf[t] = *(const short8*)&Bh[br];
            blf[t] = *(const short8*)&Bl[br];
        }
#pragma unroll
        for (int i = 0; i < 4; i++) {
#pragma unroll
            for (int j = 0; j < 4; j++) {
                acc[i][j] = __builtin_amdgcn_mfma_f32_16x16x32_bf16(ahf[i], bhf[j], acc[i][j], 0, 0, 0);
                acc[i][j] = __builtin_amdgcn_mfma_f32_16x16x32_bf16(ahf[i], blf[j], acc[i][j], 0, 0, 0);
                acc[i][j] = __builtin_amdgcn_mfma_f32_16x16x32_bf16(alf[i], bhf[j], acc[i][j], 0, 0, 0);
            }
        }
    }

    const int colL = lane & 15;
    const int quad = lane >> 4;
#pragma unroll
    for (int j = 0; j < 4; j++) {
        int c = wn + j * 16 + colL;
        float bj = bias ? bias[c] : 0.0f;
#pragma unroll
        for (int i = 0; i < 4; i++) {
            int rbase = m0 + wm + i * 16 + quad * 4;
#pragma unroll
            for (int r = 0; r < 4; r++) {
                int row = rbase + r;
                if (row < M) {
                    float v = acc[i][j][r] + bj;
                    v = fmaxf(v, 0.0f);
                    size_t crow = jobA ? (size_t)lsd[row - m0] : (size_t)row;
                    C[crow * 256 + c] = v;
                }
            }
        }
    }
}

// ---------------- Fused attention + output projection ----------------

__global__ __launch_bounds__(256) void attn_out_kernel(
    const float* __restrict__ h, const float* __restrict__ h2,
    const float* __restrict__ q1, const float* __restrict__ q2,
    const float* __restrict__ Wout, const float* __restrict__ bout,
    float* __restrict__ out, int Bn) {
    int w = threadIdx.x >> 6, lane = threadIdx.x & 63;
    int row = blockIdx.x * 4 + w;
    __shared__ __align__(16) float cbuf[4][260];
    if (row < Bn) {
        const float4 a = *(const float4*)(h  + (size_t)row * HID + lane * 4);
        const float4 p = *(const float4*)(q1 + (size_t)row * HID + lane * 4);
        const float4 b = *(const float4*)(h2 + (size_t)row * HID + lane * 4);
        const float4 q = *(const float4*)(q2 + (size_t)row * HID + lane * 4);
        float s0 = a.x * p.x + a.y * p.y + a.z * p.z + a.w * p.w;
        float s1 = b.x * q.x + b.y * q.y + b.z * q.z + b.w * q.w;
        for (int o = 32; o > 0; o >>= 1) {
            s0 += __shfl_xor(s0, o);
            s1 += __shfl_xor(s1, o);
        }
        float m  = fmaxf(s0, s1);
        float e0 = __expf(s0 - m), e1 = __expf(s1 - m);
        float inv = 1.0f / (e0 + e1);
        float a0 = e0 * inv, a1 = e1 * inv;
        float4 cv;
        cv.x = a0 * a.x + a1 * b.x; cv.y = a0 * a.y + a1 * b.y;
        cv.z = a0 * a.z + a1 * b.z; cv.w = a0 * a.w + a1 * b.w;
        *(float4*)&cbuf[w][lane * 4] = cv;
    }
    __syncthreads();
    int t = threadIdx.x;
    if (t < 4 * NCLS) {
        int r = t / NCLS, j = t % NCLS;
        int orow = blockIdx.x * 4 + r;
        if (orow < Bn) {
            float acc = bout[j];
#pragma unroll 8
            for (int k = 0; k < HID; k++) acc += cbuf[r][k] * Wout[k * NCLS + j];
            out[(size_t)orow * NCLS + j] = acc;
        }
    }
}

}  // namespace

extern "C" void kernel_launch(void* const* d_in, const int* in_sizes, int n_in,
                              void* d_out, int out_size, void* d_ws, size_t ws_size,
                              hipStream_t stream) {
    const float* x    = (const float*)d_in[0];
    const int*   src0 = (const int*)d_in[1];
    const int*   dst0 = (const int*)d_in[2];
    const int*   src1 = (const int*)d_in[3];
    const int*   dst1 = (const int*)d_in[4];
    const float* W1l  = (const float*)d_in[5];
    const float* b1   = (const float*)d_in[6];
    const float* W1r  = (const float*)d_in[7];
    const float* W2l  = (const float*)d_in[8];
    const float* b2   = (const float*)d_in[9];
    const float* W2r  = (const float*)d_in[10];
    const float* Wout = (const float*)d_in[11];
    const float* bout = (const float*)d_in[12];
    float* out = (float*)d_out;

    // ---- workspace carve-up (256B-aligned) ----
    char* ws = (char*)d_ws;
    size_t off = 0;
    auto alloc = [&](size_t bytes) {
        void* p = ws + off;
        off = (off + bytes + 255) & ~(size_t)255;
        return p;
    };
    int* cnt0  = (int*)alloc((size_t)(N1i + Bni + N1i) * sizeof(int));  // cnt0|cnt1|mask: 1 memset
    int* cnt1  = cnt0 + N1i;
    int* mask  = cnt0 + N1i + Bni;
    int* rp0   = (int*)alloc((N1i + 1) * sizeof(int));
    int* rp1   = (int*)alloc((Bni + 1) * sizeof(int));
    int* bsum0 = (int*)alloc(512 * sizeof(int));
    int* bsum1 = (int*)alloc(512 * sizeof(int));
    int* bsum2 = (int*)alloc(512 * sizeof(int));
    int* list  = (int*)alloc((size_t)N1i * sizeof(int));
    int* ilist = (int*)alloc((size_t)Bni * sizeof(int));   // identity (layer 2)
    int* nlist = (int*)alloc(256);
    int* icnt  = (int*)alloc(256);
    int* es0   = (int*)alloc(E0i * sizeof(int));
    int* es1   = (int*)alloc(E1i * sizeof(int));
    unsigned short* w1l_hi = (unsigned short*)alloc(256 * FIN * sizeof(unsigned short));
    unsigned short* w1l_lo = (unsigned short*)alloc(256 * FIN * sizeof(unsigned short));
    unsigned short* w1r_hi = (unsigned short*)alloc(256 * FIN * sizeof(unsigned short));
    unsigned short* w1r_lo = (unsigned short*)alloc(256 * FIN * sizeof(unsigned short));
    unsigned short* w2l_hi = (unsigned short*)alloc(256 * HID * sizeof(unsigned short));
    unsigned short* w2l_lo = (unsigned short*)alloc(256 * HID * sizeof(unsigned short));
    unsigned short* w2r_hi = (unsigned short*)alloc(256 * HID * sizeof(unsigned short));
    unsigned short* w2r_lo = (unsigned short*)alloc(256 * HID * sizeof(unsigned short));
    unsigned short* agg0h = (unsigned short*)alloc((size_t)N1i * FIN * sizeof(unsigned short));
    unsigned short* agg0l = (unsigned short*)alloc((size_t)N1i * FIN * sizeof(unsigned short));
    unsigned short* agg1h = (unsigned short*)alloc((size_t)Bni * HID * sizeof(unsigned short));
    unsigned short* agg1l = (unsigned short*)alloc((size_t)Bni * HID * sizeof(unsigned short));
    float* h   = (float*)alloc((size_t)N1i * HID * sizeof(float));
    float* hq1 = (float*)alloc((size_t)Bni * HID * sizeof(float));
    float* h2  = (float*)alloc((size_t)Bni * HID * sizeof(float));
    float* h2q = (float*)alloc((size_t)Bni * HID * sizeof(float));

    const int nb0 = (N1i + 255) / 256, nb1 = (Bni + 255) / 256;
    const int nmb1g = (N1i + 127) / 128;   // 782 worst case; pruned blocks exit
    const int nmbB  = (Bni + 127) / 128;   // 79

    // ---- prologue: 1 memset + 6 fused kernels (mask/list/ilist piggybacked) ----
    hipMemsetAsync(cnt0, 0, (size_t)(N1i + Bni + N1i) * sizeof(int), stream);
    wtrans_all_kernel<<<768, 256, 0, stream>>>(W1l, W1r, W2l, W2r,
        w1l_hi, w1l_lo, w1r_hi, w1r_lo, w2l_hi, w2l_lo, w2r_hi, w2r_lo);
    hist_both_kernel<<<(E0i + 2 * E1i + Bni + 255) / 256, 256, 0, stream>>>(
        dst0, dst1, src1, cnt0, cnt1, mask, ilist, icnt);
    partial_sum_both_kernel<<<nb0 + nb1 + nb0, 256, 0, stream>>>(
        cnt0, cnt1, mask, bsum0, bsum1, bsum2, nb0, nb1);
    scan_bsum_both_kernel<<<3, 512, 0, stream>>>(
        bsum0, nb0, rp0 + N1i, bsum1, nb1, rp1 + Bni, bsum2, nlist);
    scan_final_both_kernel<<<nb0 + nb1 + nb0, 256, 0, stream>>>(
        cnt0, bsum0, rp0, cnt1, bsum1, rp1, mask, bsum2, list, nb0, nb1);
    scatter_both_kernel<<<(E0i + E1i + 255) / 256, 256, 0, stream>>>(
        src0, dst0, src1, dst1, cnt0, cnt1, es0, es1);

    // ---- layer 1 (pruned): agg over needed rows + fused {h, hq1} GEMM ----
    agg_mean128_kernel<<<(N1i + 3) / 4, 256, 0, stream>>>(
        x, rp0, es0, list, nlist, agg0h, agg0l);
    gemm_dual_kernel<<<nmb1g + nmbB, 512, 0, stream>>>(
        agg0h, agg0l, x, w1l_hi, w1l_lo, w1r_hi, w1r_lo, b1, h, list, nlist,
        128, 128, nmb1g,
        x, w1r_hi, w1r_lo, hq1, Bni, 128);

    // ---- layer 2 (dense, identity list): agg + fused {h2, h2q} GEMM ----
    agg_mean256_kernel<<<(Bni + 3) / 4, 256, 0, stream>>>(h, rp1, es1, agg1h, agg1l, Bni);
    gemm_dual_kernel<<<nmbB + nmbB, 512, 0, stream>>>(
        agg1h, agg1l, h, w2l_hi, w2l_lo, w2r_hi, w2r_lo, b2, h2, ilist, icnt,
        256, 256, nmbB,
        hq1, w2r_hi, w2r_lo, h2q, Bni, 256);

    // ---- attention + output projection ----
    attn_out_kernel<<<(Bni + 3) / 4, 256, 0, stream>>>(h, h2, hq1, h2q, Wout, bout, out, Bni);
}

// Round 7
// 621.791 us; speedup vs baseline: 1.1718x; 1.0858x over previous
//
#include <hip/hip_runtime.h>
#include <cstddef>

// TwinSAGE: 2-layer GraphSAGE (mean aggr) + twin query path + 2-way layer
// attention + output projection.
// Round 10: GATED CSR BUILD. The needed-row mask (round 9) now also gates
// hist and scatter: edges whose dst is a pruned node (~33%) are skipped
// entirely (no atomic, no edge-list store). mask/ilist built in a tiny
// kernel BEFORE hist (ordering). Degrees/edge-lists of needed nodes are
// unchanged -> output bit-identical to round 9.

namespace {

constexpr int N1i  = 100000;
constexpr int Bni  = 10000;
constexpr int E0i  = 1000000;
constexpr int E1i  = 100000;
constexpr int FIN  = 128;
constexpr int HID  = 256;
constexpr int NCLS = 40;

typedef __attribute__((ext_vector_type(8))) short short8;
typedef __attribute__((ext_vector_type(8))) unsigned short ushort8;
typedef __attribute__((ext_vector_type(4))) unsigned short us4;
typedef __attribute__((ext_vector_type(4))) float floatx4;

// ---------------- mask build (must precede gated hist) ----------------

__global__ void mask_build_kernel(const int* __restrict__ src1,
                                  int* __restrict__ mask,
                                  int* __restrict__ ilist, int* __restrict__ icnt) {
    int i = blockIdx.x * blockDim.x + threadIdx.x;
    if (i < E1i) mask[src1[i]] = 1;               // rows referenced by layer-2 edges
    else if (i < E1i + Bni) {
        int j = i - E1i;
        mask[j] = 1;                               // rows < B needed (attn + agg256 self)
        ilist[j] = j;                              // identity list (layer-2 gemm job a)
        if (j == 0) *icnt = Bni;
    }
}

// ---------------- fused CSR build (mask-gated for layer 1) -------------

__global__ void hist_both_kernel(const int* __restrict__ dst0, const int* __restrict__ dst1,
                                 const int* __restrict__ mask,
                                 int* __restrict__ cnt0, int* __restrict__ cnt1) {
    int i = blockIdx.x * blockDim.x + threadIdx.x;
    if (i < E0i) {
        int dn = dst0[i];
        if (mask[dn]) atomicAdd(&cnt0[dn], 1);     // skip pruned-dst edges
    } else if (i < E0i + E1i) {
        atomicAdd(&cnt1[dst1[i - E0i]], 1);        // all layer-2 targets needed
    }
}

// jobs: 0 = cnt0 (N1), 1 = cnt1 (B), 2 = mask (N1)
__global__ void partial_sum_both_kernel(const int* __restrict__ cnt0, const int* __restrict__ cnt1,
                                        const int* __restrict__ mask,
                                        int* __restrict__ bsum0, int* __restrict__ bsum1,
                                        int* __restrict__ bsum2, int nb0, int nb1) {
    __shared__ int s[256];
    const int* cnt; int n; int* bsum; int bi;
    int bx = blockIdx.x;
    if (bx < nb0)            { cnt = cnt0; n = N1i; bsum = bsum0; bi = bx; }
    else if (bx < nb0 + nb1) { cnt = cnt1; n = Bni; bsum = bsum1; bi = bx - nb0; }
    else                     { cnt = mask; n = N1i; bsum = bsum2; bi = bx - nb0 - nb1; }
    int i = bi * 256 + threadIdx.x;
    s[threadIdx.x] = (i < n) ? cnt[i] : 0;
    __syncthreads();
    for (int o = 128; o > 0; o >>= 1) {
        if (threadIdx.x < o) s[threadIdx.x] += s[threadIdx.x + o];
        __syncthreads();
    }
    if (threadIdx.x == 0) bsum[bi] = s[0];
}

// grid = 3 blocks, 512 threads.
__global__ void scan_bsum_both_kernel(int* __restrict__ bsum0, int nb0, int* __restrict__ tot0,
                                      int* __restrict__ bsum1, int nb1, int* __restrict__ tot1,
                                      int* __restrict__ bsum2, int* __restrict__ tot2) {
    __shared__ int s[512];
    int* bsum; int nb; int* tot;
    if (blockIdx.x == 0)      { bsum = bsum0; nb = nb0; tot = tot0; }
    else if (blockIdx.x == 1) { bsum = bsum1; nb = nb1; tot = tot1; }
    else                      { bsum = bsum2; nb = nb0; tot = tot2; }
    int t = threadIdx.x;
    int v = (t < nb) ? bsum[t] : 0;
    s[t] = v;
    __syncthreads();
    for (int o = 1; o < 512; o <<= 1) {
        int u = (t >= o) ? s[t - o] : 0;
        __syncthreads();
        s[t] += u;
        __syncthreads();
    }
    if (t < nb) bsum[t] = s[t] - v;   // exclusive
    if (t == 511) *tot = s[511];
}

// jobs 0/1: rp + cursor. job 2: compact list of mask=1 rows (ascending).
__global__ void scan_final_both_kernel(int* __restrict__ cnt0, const int* __restrict__ bsum0, int* __restrict__ rp0,
                                       int* __restrict__ cnt1, const int* __restrict__ bsum1, int* __restrict__ rp1,
                                       const int* __restrict__ mask, const int* __restrict__ bsum2,
                                       int* __restrict__ list, int nb0, int nb1) {
    __shared__ int s[256];
    const int* cnt; const int* bsum; int n; int bi; int job;
    int bx = blockIdx.x;
    if (bx < nb0)            { job = 0; cnt = cnt0; bsum = bsum0; n = N1i; bi = bx; }
    else if (bx < nb0 + nb1) { job = 1; cnt = cnt1; bsum = bsum1; n = Bni; bi = bx - nb0; }
    else                     { job = 2; cnt = mask; bsum = bsum2; n = N1i; bi = bx - nb0 - nb1; }
    int t = threadIdx.x;
    int i = bi * 256 + t;
    int v = (i < n) ? cnt[i] : 0;
    s[t] = v;
    __syncthreads();
    for (int o = 1; o < 256; o <<= 1) {
        int u = (t >= o) ? s[t - o] : 0;
        __syncthreads();
        s[t] += u;
        __syncthreads();
    }
    if (i < n) {
        int r = bsum[bi] + s[t] - v;  // exclusive prefix
        if (job == 2) {
            if (v) list[r] = i;
        } else if (job == 0) {
            rp0[i] = r; cnt0[i] = r;  // cursor for scatter
        } else {
            rp1[i] = r; cnt1[i] = r;
        }
    }
}

__global__ void scatter_both_kernel(const int* __restrict__ src0, const int* __restrict__ dst0,
                                    const int* __restrict__ src1, const int* __restrict__ dst1,
                                    const int* __restrict__ mask,
                                    int* __restrict__ cur0, int* __restrict__ cur1,
                                    int* __restrict__ es0, int* __restrict__ es1) {
    int i = blockIdx.x * blockDim.x + threadIdx.x;
    if (i < E0i) {
        int dn = dst0[i];
        if (mask[dn]) {                            // skip pruned-dst edges
            int p = atomicAdd(&cur0[dn], 1);
            es0[p] = src0[i];
        }
    } else if (i < E0i + E1i) {
        int j = i - E0i;
        int p = atomicAdd(&cur1[dst1[j]], 1);
        es1[p] = src1[j];
    }
}

// ---------------- bf16 split helpers ----------------

__device__ inline unsigned short bf16_rne_u(unsigned u) {
    unsigned r = u + 0x7fffu + ((u >> 16) & 1u);
    return (unsigned short)(r >> 16);
}

__device__ inline void split1(float f, unsigned short& hs, unsigned short& ls) {
    hs = bf16_rne_u(__float_as_uint(f));
    float lo = f - __uint_as_float((unsigned)hs << 16);
    ls = bf16_rne_u(__float_as_uint(lo));
}

// ---------------- Mean aggregation (emit split hi/lo planes) ----------

__global__ __launch_bounds__(256) void agg_mean128_kernel(
    const float* __restrict__ x, const int* __restrict__ rp,
    const int* __restrict__ es, const int* __restrict__ list,
    const int* __restrict__ nlistp,
    unsigned short* __restrict__ aggh, unsigned short* __restrict__ aggl) {
    int slot = blockIdx.x * 4 + (threadIdx.x >> 6);
    if (slot >= *nlistp) return;          // wave-uniform
    int node = list[slot];
    int lane = threadIdx.x & 63;
    int b = rp[node], e = rp[node + 1];
    int d = e - b;
    int half = lane >> 5;
    int sl   = lane & 31;
    float4 acc = {0.f, 0.f, 0.f, 0.f};
    const float* xp = x + sl * 4;
    for (int base = 0; base < d; base += 64) {
        int rem = d - base; if (rem > 64) rem = 64;
        int li  = lane < rem ? lane : rem - 1;
        int idx = es[b + base + li];
        int rm1 = rem - 1;
        int npair = (rem + 1) >> 1;
        for (int p = 0; p < npair; p += 8) {
            int e0 = p * 2 + half;
            int s0 = e0      <= rm1 ? e0      : rm1;
            int s1 = e0 + 2  <= rm1 ? e0 + 2  : rm1;
            int s2 = e0 + 4  <= rm1 ? e0 + 4  : rm1;
            int s3 = e0 + 6  <= rm1 ? e0 + 6  : rm1;
            int s4 = e0 + 8  <= rm1 ? e0 + 8  : rm1;
            int s5 = e0 + 10 <= rm1 ? e0 + 10 : rm1;
            int s6 = e0 + 12 <= rm1 ? e0 + 12 : rm1;
            int s7 = e0 + 14 <= rm1 ? e0 + 14 : rm1;
            float w0 = (e0      < rem) ? 1.f : 0.f;
            float w1 = (e0 + 2  < rem) ? 1.f : 0.f;
            float w2 = (e0 + 4  < rem) ? 1.f : 0.f;
            float w3 = (e0 + 6  < rem) ? 1.f : 0.f;
            float w4 = (e0 + 8  < rem) ? 1.f : 0.f;
            float w5 = (e0 + 10 < rem) ? 1.f : 0.f;
            float w6 = (e0 + 12 < rem) ? 1.f : 0.f;
            float w7 = (e0 + 14 < rem) ? 1.f : 0.f;
            int i0 = __shfl(idx, s0), i1 = __shfl(idx, s1);
            int i2 = __shfl(idx, s2), i3 = __shfl(idx, s3);
            int i4 = __shfl(idx, s4), i5 = __shfl(idx, s5);
            int i6 = __shfl(idx, s6), i7 = __shfl(idx, s7);
            float4 v0 = *(const float4*)(xp + i0 * FIN);
            float4 v1 = *(const float4*)(xp + i1 * FIN);
            float4 v2 = *(const float4*)(xp + i2 * FIN);
            float4 v3 = *(const float4*)(xp + i3 * FIN);
            float4 v4 = *(const float4*)(xp + i4 * FIN);
            float4 v5 = *(const float4*)(xp + i5 * FIN);
            float4 v6 = *(const float4*)(xp + i6 * FIN);
            float4 v7 = *(const float4*)(xp + i7 * FIN);
            acc.x += v0.x * w0 + v1.x * w1 + v2.x * w2 + v3.x * w3
                   + v4.x * w4 + v5.x * w5 + v6.x * w6 + v7.x * w7;
            acc.y += v0.y * w0 + v1.y * w1 + v2.y * w2 + v3.y * w3
                   + v4.y * w4 + v5.y * w5 + v6.y * w6 + v7.y * w7;
            acc.z += v0.z * w0 + v1.z * w1 + v2.z * w2 + v3.z * w3
                   + v4.z * w4 + v5.z * w5 + v6.z * w6 + v7.z * w7;
            acc.w += v0.w * w0 + v1.w * w1 + v2.w * w2 + v3.w * w3
                   + v4.w * w4 + v5.w * w5 + v6.w * w6 + v7.w * w7;
        }
    }
    acc.x += __shfl_xor(acc.x, 32);
    acc.y += __shfl_xor(acc.y, 32);
    acc.z += __shfl_xor(acc.z, 32);
    acc.w += __shfl_xor(acc.w, 32);
    if (lane < 32) {
        float inv = 1.0f / fmaxf((float)d, 1.0f);
        float f[4] = {acc.x * inv, acc.y * inv, acc.z * inv, acc.w * inv};
        us4 hv, lv;
#pragma unroll
        for (int j = 0; j < 4; j++) { unsigned short hs, ls; split1(f[j], hs, ls); hv[j] = hs; lv[j] = ls; }
        *(us4*)(aggh + (size_t)slot * FIN + sl * 4) = hv;
        *(us4*)(aggl + (size_t)slot * FIN + sl * 4) = lv;
    }
}

__global__ __launch_bounds__(256) void agg_mean256_kernel(
    const float* __restrict__ h, const int* __restrict__ rp,
    const int* __restrict__ es,
    unsigned short* __restrict__ aggh, unsigned short* __restrict__ aggl, int ntgt) {
    int tgt  = blockIdx.x * 4 + (threadIdx.x >> 6);
    int lane = threadIdx.x & 63;
    if (tgt >= ntgt) return;
    int b = rp[tgt], e = rp[tgt + 1];
    int d = e - b;
    float4 acc = {0.f, 0.f, 0.f, 0.f};
    const float* hp = h + lane * 4;
    for (int base = 0; base < d; base += 64) {
        int rem = d - base; if (rem > 64) rem = 64;
        int li  = lane < rem ? lane : rem - 1;
        int idx = es[b + base + li];
        int rm1 = rem - 1;
        for (int j = 0; j < rem; j += 8) {
            int s0 = j     <= rm1 ? j     : rm1;
            int s1 = j + 1 <= rm1 ? j + 1 : rm1;
            int s2 = j + 2 <= rm1 ? j + 2 : rm1;
            int s3 = j + 3 <= rm1 ? j + 3 : rm1;
            int s4 = j + 4 <= rm1 ? j + 4 : rm1;
            int s5 = j + 5 <= rm1 ? j + 5 : rm1;
            int s6 = j + 6 <= rm1 ? j + 6 : rm1;
            int s7 = j + 7 <= rm1 ? j + 7 : rm1;
            float w0 = 1.f;
            float w1 = (j + 1 < rem) ? 1.f : 0.f;
            float w2 = (j + 2 < rem) ? 1.f : 0.f;
            float w3 = (j + 3 < rem) ? 1.f : 0.f;
            float w4 = (j + 4 < rem) ? 1.f : 0.f;
            float w5 = (j + 5 < rem) ? 1.f : 0.f;
            float w6 = (j + 6 < rem) ? 1.f : 0.f;
            float w7 = (j + 7 < rem) ? 1.f : 0.f;
            int i0 = __shfl(idx, s0), i1 = __shfl(idx, s1);
            int i2 = __shfl(idx, s2), i3 = __shfl(idx, s3);
            int i4 = __shfl(idx, s4), i5 = __shfl(idx, s5);
            int i6 = __shfl(idx, s6), i7 = __shfl(idx, s7);
            float4 v0 = *(const float4*)(hp + i0 * HID);
            float4 v1 = *(const float4*)(hp + i1 * HID);
            float4 v2 = *(const float4*)(hp + i2 * HID);
            float4 v3 = *(const float4*)(hp + i3 * HID);
            float4 v4 = *(const float4*)(hp + i4 * HID);
            float4 v5 = *(const float4*)(hp + i5 * HID);
            float4 v6 = *(const float4*)(hp + i6 * HID);
            float4 v7 = *(const float4*)(hp + i7 * HID);
            acc.x += v0.x * w0 + v1.x * w1 + v2.x * w2 + v3.x * w3
                   + v4.x * w4 + v5.x * w5 + v6.x * w6 + v7.x * w7;
            acc.y += v0.y * w0 + v1.y * w1 + v2.y * w2 + v3.y * w3
                   + v4.y * w4 + v5.y * w5 + v6.y * w6 + v7.y * w7;
            acc.z += v0.z * w0 + v1.z * w1 + v2.z * w2 + v3.z * w3
                   + v4.z * w4 + v5.z * w5 + v6.z * w6 + v7.z * w7;
            acc.w += v0.w * w0 + v1.w * w1 + v2.w * w2 + v3.w * w3
                   + v4.w * w4 + v5.w * w5 + v6.w * w6 + v7.w * w7;
        }
    }
    float inv = 1.0f / fmaxf((float)d, 1.0f);
    float f[4] = {acc.x * inv, acc.y * inv, acc.z * inv, acc.w * inv};
    us4 hv, lv;
#pragma unroll
    for (int j = 0; j < 4; j++) { unsigned short hs, ls; split1(f[j], hs, ls); hv[j] = hs; lv[j] = ls; }
    *(us4*)(aggh + (size_t)tgt * HID + lane * 4) = hv;
    *(us4*)(aggl + (size_t)tgt * HID + lane * 4) = lv;
}

// ---------------- weight transpose + bf16 hi/lo split (fused x4) --------

__global__ void wtrans_all_kernel(const float* __restrict__ W1l, const float* __restrict__ W1r,
                                  const float* __restrict__ W2l, const float* __restrict__ W2r,
                                  unsigned short* __restrict__ w1lh, unsigned short* __restrict__ w1ll,
                                  unsigned short* __restrict__ w1rh, unsigned short* __restrict__ w1rl,
                                  unsigned short* __restrict__ w2lh, unsigned short* __restrict__ w2ll,
                                  unsigned short* __restrict__ w2rh, unsigned short* __restrict__ w2rl) {
    int e = blockIdx.x * 256 + threadIdx.x;
    const float* W; unsigned short* hiT; unsigned short* loT; int K; int idx;
    if (e < 65536) {
        K = 128;
        if (e < 32768) { W = W1l; hiT = w1lh; loT = w1ll; idx = e; }
        else           { W = W1r; hiT = w1rh; loT = w1rl; idx = e - 32768; }
    } else {
        K = 256;
        int e2 = e - 65536;
        if (e2 < 65536) { W = W2l; hiT = w2lh; loT = w2ll; idx = e2; }
        else            { W = W2r; hiT = w2rh; loT = w2rl; idx = e2 - 65536; }
    }
    int k = idx >> 8, n = idx & 255;
    unsigned short hs, ls;
    split1(W[idx], hs, ls);
    hiT[n * K + k] = hs;
    loT[n * K + k] = ls;
}

// ---------------- unified split-bf16 MFMA GEMM (pruned job a) ----------

__device__ inline void cvt_store8(unsigned short* hi_dst, unsigned short* lo_dst,
                                  const float* v) {
    ushort8 hv, lv;
#pragma unroll
    for (int i = 0; i < 8; i++) {
        unsigned short hs, ls;
        split1(v[i], hs, ls);
        hv[i] = hs;
        lv[i] = ls;
    }
    *(ushort8*)hi_dst = hv;
    *(ushort8*)lo_dst = lv;
}

__global__ __launch_bounds__(512, 2) void gemm_dual_kernel(
    const unsigned short* __restrict__ A1ha, const unsigned short* __restrict__ A1la,
    const float* __restrict__ A2a,
    const unsigned short* __restrict__ B1ha, const unsigned short* __restrict__ B1la,
    const unsigned short* __restrict__ B2ha, const unsigned short* __restrict__ B2la,
    const float* __restrict__ biasa, float* __restrict__ Ca,
    const int* __restrict__ list, const int* __restrict__ nlistp,
    int K1a, int K2a, int nmba,
    const float* __restrict__ A1fb,
    const unsigned short* __restrict__ B1hb, const unsigned short* __restrict__ B1lb,
    float* __restrict__ Cb, int Mb, int K1b) {
    constexpr int LDAS = 40;  // bf16 elems per LDS row (+8 pad)
    __shared__ __align__(16) unsigned short Ah[128 * LDAS];
    __shared__ __align__(16) unsigned short Al[128 * LDAS];
    __shared__ __align__(16) unsigned short Bh[256 * LDAS];
    __shared__ __align__(16) unsigned short Bl[256 * LDAS];
    __shared__ int lsd[128];   // job a: slot -> node map

    const unsigned short *A1h, *A1l;
    const float *A1f, *A2;
    const unsigned short *B1h, *B1l, *B2h, *B2l;
    const float* bias; float* C; int K1, K2, M;
    bool jobA;
    int mb = blockIdx.x;
    if (mb < nmba) {
        jobA = true;
        M = *nlistp;
        if (mb * 128 >= M) return;          // block-uniform early exit
        A1h = A1ha; A1l = A1la; A1f = nullptr; A2 = A2a;
        B1h = B1ha; B1l = B1la; B2h = B2ha; B2l = B2la;
        bias = biasa; C = Ca; K1 = K1a; K2 = K2a;
    } else {
        jobA = false;
        mb -= nmba;
        M = Mb;
        A1h = nullptr; A1l = nullptr; A1f = A1fb; A2 = nullptr;
        B1h = B1hb; B1l = B1lb; B2h = nullptr; B2l = nullptr;
        bias = nullptr; C = Cb; K1 = K1b; K2 = 0;
    }
    const int Kt = K1 + K2;
    const int m0 = mb * 128;

    const int tid  = threadIdx.x;
    const int lane = tid & 63;
    const int wave = tid >> 6;
    const int wm   = (wave & 1) * 64;
    const int wn   = (wave >> 1) * 64;
    const int arow_l = tid >> 2;
    const int acol   = (tid & 3) * 8;
    const int brow   = tid >> 1;
    const int bcol   = (tid & 1) * 16;
    const int frow = lane & 15;
    const int fk   = (lane >> 4) * 8;

    int arow = m0 + arow_l; if (arow >= M) arow = M - 1;
    const int arl = arow - m0;           // clamped local row (0..127)

    if (jobA && tid < 128) {
        int s = m0 + tid;
        lsd[tid] = list[s < M ? s : M - 1];
    }
    // visibility: first lsd use is after the loop's first __syncthreads()

    floatx4 acc[4][4] = {};

    float4 pa0, pa1;
    ushort8 pah, pal;
    ushort8 ph0, ph1, pl0, pl1;
    if (jobA) {
        pah = *(const ushort8*)(A1h + (size_t)arow * K1 + acol);
        pal = *(const ushort8*)(A1l + (size_t)arow * K1 + acol);
    } else {
        const float* ap = A1f + (size_t)arow * K1 + acol;
        pa0 = *(const float4*)(ap);
        pa1 = *(const float4*)(ap + 4);
    }
    {
        const unsigned short* bhp = B1h + (size_t)brow * K1 + bcol;
        const unsigned short* blp = B1l + (size_t)brow * K1 + bcol;
        ph0 = *(const ushort8*)bhp;       ph1 = *(const ushort8*)(bhp + 8);
        pl0 = *(const ushort8*)blp;       pl1 = *(const ushort8*)(blp + 8);
    }

    for (int k0 = 0; k0 < Kt; k0 += 32) {
        bool splitPhase = jobA && (k0 < K1);
        __syncthreads();
        if (splitPhase) {
            *(ushort8*)&Ah[arow_l * LDAS + acol] = pah;
            *(ushort8*)&Al[arow_l * LDAS + acol] = pal;
        } else {
            float av[8] = {pa0.x, pa0.y, pa0.z, pa0.w, pa1.x, pa1.y, pa1.z, pa1.w};
            cvt_store8(&Ah[arow_l * LDAS + acol], &Al[arow_l * LDAS + acol], av);
        }
        *(ushort8*)&Bh[brow * LDAS + bcol]     = ph0;
        *(ushort8*)&Bh[brow * LDAS + bcol + 8] = ph1;
        *(ushort8*)&Bl[brow * LDAS + bcol]     = pl0;
        *(ushort8*)&Bl[brow * LDAS + bcol + 8] = pl1;
        __syncthreads();
        if (k0 + 32 < Kt) {
            int kn = k0 + 32;
            if (kn < K1) {
                if (jobA) {
                    pah = *(const ushort8*)(A1h + (size_t)arow * K1 + kn + acol);
                    pal = *(const ushort8*)(A1l + (size_t)arow * K1 + kn + acol);
                } else {
                    const float* ap = A1f + (size_t)arow * K1 + kn + acol;
                    pa0 = *(const float4*)(ap);
                    pa1 = *(const float4*)(ap + 4);
                }
                const unsigned short* bhp = B1h + (size_t)brow * K1 + kn + bcol;
                const unsigned short* blp = B1l + (size_t)brow * K1 + kn + bcol;
                ph0 = *(const ushort8*)bhp;   ph1 = *(const ushort8*)(bhp + 8);
                pl0 = *(const ushort8*)blp;   pl1 = *(const ushort8*)(blp + 8);
            } else {
                int kk = kn - K1;
                int anode = lsd[arl];                  // slot -> node
                const float* ap = A2 + (size_t)anode * K2 + kk + acol;
                pa0 = *(const float4*)(ap);
                pa1 = *(const float4*)(ap + 4);
                const unsigned short* bhp = B2h + (size_t)brow * K2 + kk + bcol;
                const unsigned short* blp = B2l + (size_t)brow * K2 + kk + bcol;
                ph0 = *(const ushort8*)bhp;   ph1 = *(const ushort8*)(bhp + 8);
                pl0 = *(const ushort8*)blp;   pl1 = *(const ushort8*)(blp + 8);
            }
        }

        short8 ahf[4], alf[4], bhf[4], blf[4];
#pragma unroll
        for (int t = 0; t < 4; t++) {
            int ar = (wm + t * 16 + frow) * LDAS + fk;
            ahf[t] = *(const short8*)&Ah[ar];
            alf[t] = *(const short8*)&Al[ar];
            int br = (wn + t * 16 + frow) * LDAS + fk;
            bhf[t] = *(const short8*)&Bh[br];
            blf[t] = *(const short8*)&Bl[br];
        }
#pragma unroll
        for (int i = 0; i < 4; i++) {
#pragma unroll
            for (int j = 0; j < 4; j++) {
                acc[i][j] = __builtin_amdgcn_mfma_f32_16x16x32_bf16(ahf[i], bhf[j], acc[i][j], 0, 0, 0);
                acc[i][j] = __builtin_amdgcn_mfma_f32_16x16x32_bf16(ahf[i], blf[j], acc[i][j], 0, 0, 0);
                acc[i][j] = __builtin_amdgcn_mfma_f32_16x16x32_bf16(alf[i], bhf[j], acc[i][j], 0, 0, 0);
            }
        }
    }

    const int colL = lane & 15;
    const int quad = lane >> 4;
#pragma unroll
    for (int j = 0; j < 4; j++) {
        int c = wn + j * 16 + colL;
        float bj = bias ? bias[c] : 0.0f;
#pragma unroll
        for (int i = 0; i < 4; i++) {
            int rbase = m0 + wm + i * 16 + quad * 4;
#pragma unroll
            for (int r = 0; r < 4; r++) {
                int row = rbase + r;
                if (row < M) {
                    float v = acc[i][j][r] + bj;
                    v = fmaxf(v, 0.0f);
                    size_t crow = jobA ? (size_t)lsd[row - m0] : (size_t)row;
                    C[crow * 256 + c] = v;
                }
            }
        }
    }
}

// ---------------- Fused attention + output projection ----------------

__global__ __launch_bounds__(256) void attn_out_kernel(
    const float* __restrict__ h, const float* __restrict__ h2,
    const float* __restrict__ q1, const float* __restrict__ q2,
    const float* __restrict__ Wout, const float* __restrict__ bout,
    float* __restrict__ out, int Bn) {
    int w = threadIdx.x >> 6, lane = threadIdx.x & 63;
    int row = blockIdx.x * 4 + w;
    __shared__ __align__(16) float cbuf[4][260];
    if (row < Bn) {
        const float4 a = *(const float4*)(h  + (size_t)row * HID + lane * 4);
        const float4 p = *(const float4*)(q1 + (size_t)row * HID + lane * 4);
        const float4 b = *(const float4*)(h2 + (size_t)row * HID + lane * 4);
        const float4 q = *(const float4*)(q2 + (size_t)row * HID + lane * 4);
        float s0 = a.x * p.x + a.y * p.y + a.z * p.z + a.w * p.w;
        float s1 = b.x * q.x + b.y * q.y + b.z * q.z + b.w * q.w;
        for (int o = 32; o > 0; o >>= 1) {
            s0 += __shfl_xor(s0, o);
            s1 += __shfl_xor(s1, o);
        }
        float m  = fmaxf(s0, s1);
        float e0 = __expf(s0 - m), e1 = __expf(s1 - m);
        float inv = 1.0f / (e0 + e1);
        float a0 = e0 * inv, a1 = e1 * inv;
        float4 cv;
        cv.x = a0 * a.x + a1 * b.x; cv.y = a0 * a.y + a1 * b.y;
        cv.z = a0 * a.z + a1 * b.z; cv.w = a0 * a.w + a1 * b.w;
        *(float4*)&cbuf[w][lane * 4] = cv;
    }
    __syncthreads();
    int t = threadIdx.x;
    if (t < 4 * NCLS) {
        int r = t / NCLS, j = t % NCLS;
        int orow = blockIdx.x * 4 + r;
        if (orow < Bn) {
            float acc = bout[j];
#pragma unroll 8
            for (int k = 0; k < HID; k++) acc += cbuf[r][k] * Wout[k * NCLS + j];
            out[(size_t)orow * NCLS + j] = acc;
        }
    }
}

}  // namespace

extern "C" void kernel_launch(void* const* d_in, const int* in_sizes, int n_in,
                              void* d_out, int out_size, void* d_ws, size_t ws_size,
                              hipStream_t stream) {
    const float* x    = (const float*)d_in[0];
    const int*   src0 = (const int*)d_in[1];
    const int*   dst0 = (const int*)d_in[2];
    const int*   src1 = (const int*)d_in[3];
    const int*   dst1 = (const int*)d_in[4];
    const float* W1l  = (const float*)d_in[5];
    const float* b1   = (const float*)d_in[6];
    const float* W1r  = (const float*)d_in[7];
    const float* W2l  = (const float*)d_in[8];
    const float* b2   = (const float*)d_in[9];
    const float* W2r  = (const float*)d_in[10];
    const float* Wout = (const float*)d_in[11];
    const float* bout = (const float*)d_in[12];
    float* out = (float*)d_out;

    // ---- workspace carve-up (256B-aligned) ----
    char* ws = (char*)d_ws;
    size_t off = 0;
    auto alloc = [&](size_t bytes) {
        void* p = ws + off;
        off = (off + bytes + 255) & ~(size_t)255;
        return p;
    };
    int* cnt0  = (int*)alloc((size_t)(N1i + Bni + N1i) * sizeof(int));  // cnt0|cnt1|mask: 1 memset
    int* cnt1  = cnt0 + N1i;
    int* mask  = cnt0 + N1i + Bni;
    int* rp0   = (int*)alloc((N1i + 1) * sizeof(int));
    int* rp1   = (int*)alloc((Bni + 1) * sizeof(int));
    int* bsum0 = (int*)alloc(512 * sizeof(int));
    int* bsum1 = (int*)alloc(512 * sizeof(int));
    int* bsum2 = (int*)alloc(512 * sizeof(int));
    int* list  = (int*)alloc((size_t)N1i * sizeof(int));
    int* ilist = (int*)alloc((size_t)Bni * sizeof(int));   // identity (layer 2)
    int* nlist = (int*)alloc(256);
    int* icnt  = (int*)alloc(256);
    int* es0   = (int*)alloc(E0i * sizeof(int));
    int* es1   = (int*)alloc(E1i * sizeof(int));
    unsigned short* w1l_hi = (unsigned short*)alloc(256 * FIN * sizeof(unsigned short));
    unsigned short* w1l_lo = (unsigned short*)alloc(256 * FIN * sizeof(unsigned short));
    unsigned short* w1r_hi = (unsigned short*)alloc(256 * FIN * sizeof(unsigned short));
    unsigned short* w1r_lo = (unsigned short*)alloc(256 * FIN * sizeof(unsigned short));
    unsigned short* w2l_hi = (unsigned short*)alloc(256 * HID * sizeof(unsigned short));
    unsigned short* w2l_lo = (unsigned short*)alloc(256 * HID * sizeof(unsigned short));
    unsigned short* w2r_hi = (unsigned short*)alloc(256 * HID * sizeof(unsigned short));
    unsigned short* w2r_lo = (unsigned short*)alloc(256 * HID * sizeof(unsigned short));
    unsigned short* agg0h = (unsigned short*)alloc((size_t)N1i * FIN * sizeof(unsigned short));
    unsigned short* agg0l = (unsigned short*)alloc((size_t)N1i * FIN * sizeof(unsigned short));
    unsigned short* agg1h = (unsigned short*)alloc((size_t)Bni * HID * sizeof(unsigned short));
    unsigned short* agg1l = (unsigned short*)alloc((size_t)Bni * HID * sizeof(unsigned short));
    float* h   = (float*)alloc((size_t)N1i * HID * sizeof(float));
    float* hq1 = (float*)alloc((size_t)Bni * HID * sizeof(float));
    float* h2  = (float*)alloc((size_t)Bni * HID * sizeof(float));
    float* h2q = (float*)alloc((size_t)Bni * HID * sizeof(float));

    const int nb0 = (N1i + 255) / 256, nb1 = (Bni + 255) / 256;
    const int nmb1g = (N1i + 127) / 128;   // worst case; pruned blocks exit
    const int nmbB  = (Bni + 127) / 128;   // 79

    // ---- prologue: 1 memset + 7 fused kernels ----
    hipMemsetAsync(cnt0, 0, (size_t)(N1i + Bni + N1i) * sizeof(int), stream);
    mask_build_kernel<<<(E1i + Bni + 255) / 256, 256, 0, stream>>>(src1, mask, ilist, icnt);
    wtrans_all_kernel<<<768, 256, 0, stream>>>(W1l, W1r, W2l, W2r,
        w1l_hi, w1l_lo, w1r_hi, w1r_lo, w2l_hi, w2l_lo, w2r_hi, w2r_lo);
    hist_both_kernel<<<(E0i + E1i + 255) / 256, 256, 0, stream>>>(
        dst0, dst1, mask, cnt0, cnt1);
    partial_sum_both_kernel<<<nb0 + nb1 + nb0, 256, 0, stream>>>(
        cnt0, cnt1, mask, bsum0, bsum1, bsum2, nb0, nb1);
    scan_bsum_both_kernel<<<3, 512, 0, stream>>>(
        bsum0, nb0, rp0 + N1i, bsum1, nb1, rp1 + Bni, bsum2, nlist);
    scan_final_both_kernel<<<nb0 + nb1 + nb0, 256, 0, stream>>>(
        cnt0, bsum0, rp0, cnt1, bsum1, rp1, mask, bsum2, list, nb0, nb1);
    scatter_both_kernel<<<(E0i + E1i + 255) / 256, 256, 0, stream>>>(
        src0, dst0, src1, dst1, mask, cnt0, cnt1, es0, es1);

    // ---- layer 1 (pruned): agg over needed rows + fused {h, hq1} GEMM ----
    agg_mean128_kernel<<<(N1i + 3) / 4, 256, 0, stream>>>(
        x, rp0, es0, list, nlist, agg0h, agg0l);
    gemm_dual_kernel<<<nmb1g + nmbB, 512, 0, stream>>>(
        agg0h, agg0l, x, w1l_hi, w1l_lo, w1r_hi, w1r_lo, b1, h, list, nlist,
        128, 128, nmb1g,
        x, w1r_hi, w1r_lo, hq1, Bni, 128);

    // ---- layer 2 (dense, identity list): agg + fused {h2, h2q} GEMM ----
    agg_mean256_kernel<<<(Bni + 3) / 4, 256, 0, stream>>>(h, rp1, es1, agg1h, agg1l, Bni);
    gemm_dual_kernel<<<nmbB + nmbB, 512, 0, stream>>>(
        agg1h, agg1l, h, w2l_hi, w2l_lo, w2r_hi, w2r_lo, b2, h2, ilist, icnt,
        256, 256, nmbB,
        hq1, w2r_hi, w2r_lo, h2q, Bni, 256);

    // ---- attention + output projection ----
    attn_out_kernel<<<(Bni + 3) / 4, 256, 0, stream>>>(h, h2, hq1, h2q, Wout, bout, out, Bni);
}